// Round 1
// baseline (2160.870 us; speedup 1.0000x reference)
//
#include <hip/hip_runtime.h>
#include <math.h>

#define N_NODES 100000
#define M_EDGES 800000
#define HID 128
#define HEADS 8
#define DH 16

// ---------------------------------------------------------------------------
// Kernel 1: fused Q/K/V projection.  q,k,v[n,c] = dot(feats[n,:], W[c,:])
// Block = 256 threads handles 64 rows x 128 cols for all three W matrices.
// feats tile staged in LDS; W rows stream from L2 (64KB each, stays hot).
// Thread map: tx = tid&31 -> cols tx*4..tx*4+3 ; ty = tid>>5 -> rows ty*8..ty*8+7
// ---------------------------------------------------------------------------
__global__ __launch_bounds__(256) void qkv_kernel(
    const float* __restrict__ feats,
    const float* __restrict__ Wq, const float* __restrict__ Wk, const float* __restrict__ Wv,
    float* __restrict__ q, float* __restrict__ k, float* __restrict__ v)
{
    __shared__ float As[64][HID];
    const int row0 = blockIdx.x * 64;
    const int tid = threadIdx.x;

    // stage feats tile (64x128 fp32 = 32KB)
    for (int i = tid; i < 64 * 32; i += 256) {
        int r = i >> 5, c = i & 31;
        int row = row0 + r;
        float4 val = make_float4(0.f, 0.f, 0.f, 0.f);
        if (row < N_NODES) val = ((const float4*)feats)[row * 32 + c];
        ((float4*)&As[r][0])[c] = val;
    }
    __syncthreads();

    const int tx = tid & 31;
    const int ty = tid >> 5;

    const float* Wmat[3] = {Wq, Wk, Wv};
    float*       Omat[3] = {q, k, v};

    #pragma unroll
    for (int w = 0; w < 3; ++w) {
        const float4* W4 = (const float4*)Wmat[w];
        float acc[8][4];
        #pragma unroll
        for (int r = 0; r < 8; ++r)
            #pragma unroll
            for (int c = 0; c < 4; ++c) acc[r][c] = 0.f;

        #pragma unroll 4
        for (int kk = 0; kk < 32; ++kk) {  // K in steps of 4 floats
            float4 b0 = W4[(tx * 4 + 0) * 32 + kk];
            float4 b1 = W4[(tx * 4 + 1) * 32 + kk];
            float4 b2 = W4[(tx * 4 + 2) * 32 + kk];
            float4 b3 = W4[(tx * 4 + 3) * 32 + kk];
            #pragma unroll
            for (int r = 0; r < 8; ++r) {
                float4 a = ((const float4*)&As[ty * 8 + r][0])[kk];
                acc[r][0] += a.x * b0.x + a.y * b0.y + a.z * b0.z + a.w * b0.w;
                acc[r][1] += a.x * b1.x + a.y * b1.y + a.z * b1.z + a.w * b1.w;
                acc[r][2] += a.x * b2.x + a.y * b2.y + a.z * b2.z + a.w * b2.w;
                acc[r][3] += a.x * b3.x + a.y * b3.y + a.z * b3.z + a.w * b3.w;
            }
        }
        #pragma unroll
        for (int r = 0; r < 8; ++r) {
            int row = row0 + ty * 8 + r;
            if (row < N_NODES) {
                float4 o = make_float4(acc[r][0], acc[r][1], acc[r][2], acc[r][3]);
                ((float4*)Omat[w])[row * 32 + tx] = o;
            }
        }
    }
}

// ---------------------------------------------------------------------------
// Kernel 2: per-edge, per-head attention score + denom accumulation.
// One thread per (m, h): 16-wide dot, leaky_relu(0.2), exp, atomicAdd to denom.
// ---------------------------------------------------------------------------
__global__ __launch_bounds__(256) void att_kernel(
    const int* __restrict__ idx_kj, const int* __restrict__ idx_ji,
    const float* __restrict__ q, const float* __restrict__ k,
    float* __restrict__ att, float* __restrict__ denom)
{
    int gid = blockIdx.x * 256 + threadIdx.x;
    if (gid >= M_EDGES * HEADS) return;
    int m = gid >> 3;
    int h = gid & 7;
    int kj = idx_kj[m];
    int ji = idx_ji[m];
    const float4* q4 = (const float4*)(q + (size_t)kj * HID + h * DH);
    const float4* k4 = (const float4*)(k + (size_t)ji * HID + h * DH);
    float s = 0.f;
    #pragma unroll
    for (int i = 0; i < 4; ++i) {
        float4 a = q4[i], b = k4[i];
        s += a.x * b.x + a.y * b.y + a.z * b.z + a.w * b.w;
    }
    s = (s >= 0.f) ? s : 0.2f * s;   // leaky_relu, slope 0.2
    s = expf(s);                     // unsafe softmax, as in source
    att[gid] = s;
    atomicAdd(&denom[(size_t)ji * HEADS + h], s);
}

// ---------------------------------------------------------------------------
// Kernel 3: v_att scatter.  32 threads per edge, float4 per thread,
// 4 fp32 atomicAdds into agg[idx_ji].
// ---------------------------------------------------------------------------
__global__ __launch_bounds__(256) void scatter_kernel(
    const int* __restrict__ idx_kj, const int* __restrict__ idx_ji,
    const float* __restrict__ v, const float* __restrict__ att,
    const float* __restrict__ denom, float* __restrict__ agg)
{
    int gid = blockIdx.x * 256 + threadIdx.x;
    if (gid >= M_EDGES * 32) return;
    int m = gid >> 5;
    int t = gid & 31;          // float4 slot within the 128-dim row
    int h = t >> 2;            // head = (t*4)/16
    int kj = idx_kj[m];
    int ji = idx_ji[m];
    float a = att[m * HEADS + h] / denom[(size_t)ji * HEADS + h];
    float4 vv = ((const float4*)(v + (size_t)kj * HID))[t];
    float* dst = agg + (size_t)ji * HID + t * 4;
    atomicAdd(dst + 0, vv.x * a);
    atomicAdd(dst + 1, vv.y * a);
    atomicAdd(dst + 2, vv.z * a);
    atomicAdd(dst + 3, vv.w * a);
}

// ---------------------------------------------------------------------------
// Kernel 4: residual MLP.  h1 = relu(agg@W1.T + b1); h2 = relu(h1@W2.T + b2);
// out = v + h2.  agg lives in d_out; each block reads its own 64 rows into LDS
// before overwriting them, so in-place is safe.
// ---------------------------------------------------------------------------
__global__ __launch_bounds__(256) void mlp_kernel(
    const float* __restrict__ agg, const float* __restrict__ v,
    const float* __restrict__ W1, const float* __restrict__ b1,
    const float* __restrict__ W2, const float* __restrict__ b2,
    float* __restrict__ out)
{
    __shared__ float As[64][HID];
    __shared__ float Hs[64][HID];
    const int row0 = blockIdx.x * 64;
    const int tid = threadIdx.x;

    for (int i = tid; i < 64 * 32; i += 256) {
        int r = i >> 5, c = i & 31;
        int row = row0 + r;
        float4 val = make_float4(0.f, 0.f, 0.f, 0.f);
        if (row < N_NODES) val = ((const float4*)agg)[row * 32 + c];
        ((float4*)&As[r][0])[c] = val;
    }
    __syncthreads();

    const int tx = tid & 31;
    const int ty = tid >> 5;

    // phase 1: h1 = relu(agg @ W1.T + b1) -> Hs
    {
        const float4* W4 = (const float4*)W1;
        float acc[8][4];
        #pragma unroll
        for (int r = 0; r < 8; ++r)
            #pragma unroll
            for (int c = 0; c < 4; ++c) acc[r][c] = 0.f;
        #pragma unroll 4
        for (int kk = 0; kk < 32; ++kk) {
            float4 b0 = W4[(tx * 4 + 0) * 32 + kk];
            float4 b1v = W4[(tx * 4 + 1) * 32 + kk];
            float4 b2v = W4[(tx * 4 + 2) * 32 + kk];
            float4 b3v = W4[(tx * 4 + 3) * 32 + kk];
            #pragma unroll
            for (int r = 0; r < 8; ++r) {
                float4 a = ((const float4*)&As[ty * 8 + r][0])[kk];
                acc[r][0] += a.x * b0.x + a.y * b0.y + a.z * b0.z + a.w * b0.w;
                acc[r][1] += a.x * b1v.x + a.y * b1v.y + a.z * b1v.z + a.w * b1v.w;
                acc[r][2] += a.x * b2v.x + a.y * b2v.y + a.z * b2v.z + a.w * b2v.w;
                acc[r][3] += a.x * b3v.x + a.y * b3v.y + a.z * b3v.z + a.w * b3v.w;
            }
        }
        float4 bias = ((const float4*)b1)[tx];
        #pragma unroll
        for (int r = 0; r < 8; ++r) {
            float4 o;
            o.x = fmaxf(acc[r][0] + bias.x, 0.f);
            o.y = fmaxf(acc[r][1] + bias.y, 0.f);
            o.z = fmaxf(acc[r][2] + bias.z, 0.f);
            o.w = fmaxf(acc[r][3] + bias.w, 0.f);
            ((float4*)&Hs[ty * 8 + r][0])[tx] = o;
        }
    }
    __syncthreads();

    // phase 2: h2 = relu(h1 @ W2.T + b2); out = v + h2
    {
        const float4* W4 = (const float4*)W2;
        float acc[8][4];
        #pragma unroll
        for (int r = 0; r < 8; ++r)
            #pragma unroll
            for (int c = 0; c < 4; ++c) acc[r][c] = 0.f;
        #pragma unroll 4
        for (int kk = 0; kk < 32; ++kk) {
            float4 b0 = W4[(tx * 4 + 0) * 32 + kk];
            float4 b1v = W4[(tx * 4 + 1) * 32 + kk];
            float4 b2v = W4[(tx * 4 + 2) * 32 + kk];
            float4 b3v = W4[(tx * 4 + 3) * 32 + kk];
            #pragma unroll
            for (int r = 0; r < 8; ++r) {
                float4 a = ((const float4*)&Hs[ty * 8 + r][0])[kk];
                acc[r][0] += a.x * b0.x + a.y * b0.y + a.z * b0.z + a.w * b0.w;
                acc[r][1] += a.x * b1v.x + a.y * b1v.y + a.z * b1v.z + a.w * b1v.w;
                acc[r][2] += a.x * b2v.x + a.y * b2v.y + a.z * b2v.z + a.w * b2v.w;
                acc[r][3] += a.x * b3v.x + a.y * b3v.y + a.z * b3v.z + a.w * b3v.w;
            }
        }
        float4 bias = ((const float4*)b2)[tx];
        #pragma unroll
        for (int r = 0; r < 8; ++r) {
            int row = row0 + ty * 8 + r;
            if (row < N_NODES) {
                float4 vv = ((const float4*)v)[row * 32 + tx];
                float4 o;
                o.x = vv.x + fmaxf(acc[r][0] + bias.x, 0.f);
                o.y = vv.y + fmaxf(acc[r][1] + bias.y, 0.f);
                o.z = vv.z + fmaxf(acc[r][2] + bias.z, 0.f);
                o.w = vv.w + fmaxf(acc[r][3] + bias.w, 0.f);
                ((float4*)out)[row * 32 + tx] = o;
            }
        }
    }
}

extern "C" void kernel_launch(void* const* d_in, const int* in_sizes, int n_in,
                              void* d_out, int out_size, void* d_ws, size_t ws_size,
                              hipStream_t stream) {
    const float* feats  = (const float*)d_in[0];
    const int*   idx_kj = (const int*)d_in[1];
    const int*   idx_ji = (const int*)d_in[2];
    const float* Wv     = (const float*)d_in[3];
    const float* Wq     = (const float*)d_in[4];
    const float* Wk     = (const float*)d_in[5];
    const float* W1     = (const float*)d_in[6];
    const float* b1     = (const float*)d_in[7];
    const float* W2     = (const float*)d_in[8];
    const float* b2     = (const float*)d_in[9];
    float* out = (float*)d_out;

    // workspace layout (fp32): q, k, v, att, denom.  agg lives in d_out.
    float* ws    = (float*)d_ws;
    float* q     = ws;
    float* k     = q + (size_t)N_NODES * HID;
    float* v     = k + (size_t)N_NODES * HID;
    float* att   = v + (size_t)N_NODES * HID;
    float* denom = att + (size_t)M_EDGES * HEADS;
    float* agg   = out;   // accumulated in-place, consumed by mlp_kernel

    hipMemsetAsync(denom, 0, (size_t)N_NODES * HEADS * sizeof(float), stream);
    hipMemsetAsync(agg,   0, (size_t)N_NODES * HID   * sizeof(float), stream);

    qkv_kernel<<<(N_NODES + 63) / 64, 256, 0, stream>>>(feats, Wq, Wk, Wv, q, k, v);
    att_kernel<<<(M_EDGES * HEADS + 255) / 256, 256, 0, stream>>>(idx_kj, idx_ji, q, k, att, denom);
    scatter_kernel<<<(M_EDGES * 32 + 255) / 256, 256, 0, stream>>>(idx_kj, idx_ji, v, att, denom, agg);
    mlp_kernel<<<(N_NODES + 63) / 64, 256, 0, stream>>>(agg, v, W1, b1, W2, b2, out);
}

// Round 2
// 1156.896 us; speedup vs baseline: 1.8678x; 1.8678x over previous
//
#include <hip/hip_runtime.h>
#include <math.h>

#define N_NODES 100000
#define M_EDGES 800000
#define HID 128
#define HEADS 8
#define DH 16

// ---------------------------------------------------------------------------
// Kernel 1: fused Q/K/V projection.  q,k,v[n,c] = dot(feats[n,:], W[c,:])
// Block = 256 threads handles 64 rows x 128 cols for all three W matrices.
// ---------------------------------------------------------------------------
__global__ __launch_bounds__(256) void qkv_kernel(
    const float* __restrict__ feats,
    const float* __restrict__ Wq, const float* __restrict__ Wk, const float* __restrict__ Wv,
    float* __restrict__ q, float* __restrict__ k, float* __restrict__ v)
{
    __shared__ float As[64][HID];
    const int row0 = blockIdx.x * 64;
    const int tid = threadIdx.x;

    for (int i = tid; i < 64 * 32; i += 256) {
        int r = i >> 5, c = i & 31;
        int row = row0 + r;
        float4 val = make_float4(0.f, 0.f, 0.f, 0.f);
        if (row < N_NODES) val = ((const float4*)feats)[row * 32 + c];
        ((float4*)&As[r][0])[c] = val;
    }
    __syncthreads();

    const int tx = tid & 31;
    const int ty = tid >> 5;

    const float* Wmat[3] = {Wq, Wk, Wv};
    float*       Omat[3] = {q, k, v};

    #pragma unroll
    for (int w = 0; w < 3; ++w) {
        const float4* W4 = (const float4*)Wmat[w];
        float acc[8][4];
        #pragma unroll
        for (int r = 0; r < 8; ++r)
            #pragma unroll
            for (int c = 0; c < 4; ++c) acc[r][c] = 0.f;

        #pragma unroll 4
        for (int kk = 0; kk < 32; ++kk) {
            float4 b0 = W4[(tx * 4 + 0) * 32 + kk];
            float4 b1 = W4[(tx * 4 + 1) * 32 + kk];
            float4 b2 = W4[(tx * 4 + 2) * 32 + kk];
            float4 b3 = W4[(tx * 4 + 3) * 32 + kk];
            #pragma unroll
            for (int r = 0; r < 8; ++r) {
                float4 a = ((const float4*)&As[ty * 8 + r][0])[kk];
                acc[r][0] += a.x * b0.x + a.y * b0.y + a.z * b0.z + a.w * b0.w;
                acc[r][1] += a.x * b1.x + a.y * b1.y + a.z * b1.z + a.w * b1.w;
                acc[r][2] += a.x * b2.x + a.y * b2.y + a.z * b2.z + a.w * b2.w;
                acc[r][3] += a.x * b3.x + a.y * b3.y + a.z * b3.z + a.w * b3.w;
            }
        }
        #pragma unroll
        for (int r = 0; r < 8; ++r) {
            int row = row0 + ty * 8 + r;
            if (row < N_NODES) {
                float4 o = make_float4(acc[r][0], acc[r][1], acc[r][2], acc[r][3]);
                ((float4*)Omat[w])[row * 32 + tx] = o;
            }
        }
    }
}

// ---------------------------------------------------------------------------
// Kernel 2: histogram of destination indices.  count[ji]++ per edge.
// ---------------------------------------------------------------------------
__global__ __launch_bounds__(256) void hist_kernel(
    const int* __restrict__ idx_ji, int* __restrict__ count)
{
    int m = blockIdx.x * 256 + threadIdx.x;
    if (m < M_EDGES) atomicAdd(&count[idx_ji[m]], 1);
}

// ---------------------------------------------------------------------------
// Kernel 3: exclusive scan of count -> offsets (and a second copy, cursor).
// Single block of 1024 threads; each thread owns a contiguous chunk.
// ---------------------------------------------------------------------------
__global__ __launch_bounds__(1024) void scan_kernel(
    const int* __restrict__ count, int* __restrict__ offsets, int* __restrict__ cursor)
{
    __shared__ int sdata[1024];
    const int t = threadIdx.x;
    const int CHUNK = (N_NODES + 1023) / 1024;   // 98
    const int start = t * CHUNK;
    const int end   = min(start + CHUNK, N_NODES);

    int partial = 0;
    for (int i = start; i < end; ++i) partial += count[i];
    sdata[t] = partial;
    __syncthreads();

    // Hillis-Steele inclusive scan over 1024 partials
    for (int off = 1; off < 1024; off <<= 1) {
        int val = (t >= off) ? sdata[t - off] : 0;
        __syncthreads();
        sdata[t] += val;
        __syncthreads();
    }

    int base = sdata[t] - partial;   // exclusive prefix for this chunk
    for (int i = start; i < end; ++i) {
        offsets[i] = base;
        cursor[i]  = base;
        base += count[i];
    }
}

// ---------------------------------------------------------------------------
// Kernel 4: fill CSR edge list.  edge_list[cursor[ji]++] = m.
// ---------------------------------------------------------------------------
__global__ __launch_bounds__(256) void fill_kernel(
    const int* __restrict__ idx_ji, int* __restrict__ cursor, int* __restrict__ edge_list)
{
    int m = blockIdx.x * 256 + threadIdx.x;
    if (m < M_EDGES) {
        int pos = atomicAdd(&cursor[idx_ji[m]], 1);
        edge_list[pos] = m;
    }
}

// ---------------------------------------------------------------------------
// Kernel 5: fused attention-score + normalized aggregation, gather-style.
// One wave (64 lanes) per destination node n.  Lane holds channels
// 2*lane, 2*lane+1 (head = lane/8).  k[n] stays in registers.  Per edge:
// gather q[kj] -> score via 3x shfl_xor within the 8-lane head group,
// leaky_relu + exp, then acc += att * v[kj].  denom accumulates per-lane
// (identical across a head's 8 lanes).  Final: agg = acc / denom.
// Zero atomics; one coalesced write per node.
// ---------------------------------------------------------------------------
__global__ __launch_bounds__(256) void aggregate_kernel(
    const int* __restrict__ edge_list, const int* __restrict__ offsets,
    const int* __restrict__ count, const int* __restrict__ idx_kj,
    const float* __restrict__ q, const float* __restrict__ k, const float* __restrict__ v,
    float* __restrict__ agg)
{
    int gid  = blockIdx.x * 256 + threadIdx.x;
    int node = gid >> 6;
    int lane = threadIdx.x & 63;
    if (node >= N_NODES) return;

    const int deg  = count[node];
    const int base = offsets[node];

    const float2 kn = ((const float2*)(k + (size_t)node * HID))[lane];
    float2 acc = make_float2(0.f, 0.f);
    float  d   = 0.f;

    for (int e = 0; e < deg; ++e) {
        int m  = edge_list[base + e];
        int kj = idx_kj[m];
        float2 qv = ((const float2*)(q + (size_t)kj * HID))[lane];
        float partial = qv.x * kn.x + qv.y * kn.y;
        // reduce across the 8 lanes of this head (lanes h*8 .. h*8+7)
        partial += __shfl_xor(partial, 1);
        partial += __shfl_xor(partial, 2);
        partial += __shfl_xor(partial, 4);
        float s = (partial >= 0.f) ? partial : 0.2f * partial;  // leaky_relu(0.2)
        s = expf(s);
        d += s;
        float2 vv = ((const float2*)(v + (size_t)kj * HID))[lane];
        acc.x += s * vv.x;
        acc.y += s * vv.y;
    }

    const float inv = (deg > 0) ? 1.f / d : 0.f;   // deg==0 -> zeros, not NaN
    ((float2*)(agg + (size_t)node * HID))[lane] = make_float2(acc.x * inv, acc.y * inv);
}

// ---------------------------------------------------------------------------
// Kernel 6: residual MLP.  out = v + relu(relu(agg@W1.T+b1)@W2.T+b2).
// agg lives in d_out; each block stages its own 64 rows in LDS first,
// so in-place is safe.
// ---------------------------------------------------------------------------
__global__ __launch_bounds__(256) void mlp_kernel(
    const float* __restrict__ agg, const float* __restrict__ v,
    const float* __restrict__ W1, const float* __restrict__ b1,
    const float* __restrict__ W2, const float* __restrict__ b2,
    float* __restrict__ out)
{
    __shared__ float As[64][HID];
    __shared__ float Hs[64][HID];
    const int row0 = blockIdx.x * 64;
    const int tid = threadIdx.x;

    for (int i = tid; i < 64 * 32; i += 256) {
        int r = i >> 5, c = i & 31;
        int row = row0 + r;
        float4 val = make_float4(0.f, 0.f, 0.f, 0.f);
        if (row < N_NODES) val = ((const float4*)agg)[row * 32 + c];
        ((float4*)&As[r][0])[c] = val;
    }
    __syncthreads();

    const int tx = tid & 31;
    const int ty = tid >> 5;

    // phase 1: h1 = relu(agg @ W1.T + b1) -> Hs
    {
        const float4* W4 = (const float4*)W1;
        float acc[8][4];
        #pragma unroll
        for (int r = 0; r < 8; ++r)
            #pragma unroll
            for (int c = 0; c < 4; ++c) acc[r][c] = 0.f;
        #pragma unroll 4
        for (int kk = 0; kk < 32; ++kk) {
            float4 b0 = W4[(tx * 4 + 0) * 32 + kk];
            float4 b1v = W4[(tx * 4 + 1) * 32 + kk];
            float4 b2v = W4[(tx * 4 + 2) * 32 + kk];
            float4 b3v = W4[(tx * 4 + 3) * 32 + kk];
            #pragma unroll
            for (int r = 0; r < 8; ++r) {
                float4 a = ((const float4*)&As[ty * 8 + r][0])[kk];
                acc[r][0] += a.x * b0.x + a.y * b0.y + a.z * b0.z + a.w * b0.w;
                acc[r][1] += a.x * b1v.x + a.y * b1v.y + a.z * b1v.z + a.w * b1v.w;
                acc[r][2] += a.x * b2v.x + a.y * b2v.y + a.z * b2v.z + a.w * b2v.w;
                acc[r][3] += a.x * b3v.x + a.y * b3v.y + a.z * b3v.z + a.w * b3v.w;
            }
        }
        float4 bias = ((const float4*)b1)[tx];
        #pragma unroll
        for (int r = 0; r < 8; ++r) {
            float4 o;
            o.x = fmaxf(acc[r][0] + bias.x, 0.f);
            o.y = fmaxf(acc[r][1] + bias.y, 0.f);
            o.z = fmaxf(acc[r][2] + bias.z, 0.f);
            o.w = fmaxf(acc[r][3] + bias.w, 0.f);
            ((float4*)&Hs[ty * 8 + r][0])[tx] = o;
        }
    }
    __syncthreads();

    // phase 2: h2 = relu(h1 @ W2.T + b2); out = v + h2
    {
        const float4* W4 = (const float4*)W2;
        float acc[8][4];
        #pragma unroll
        for (int r = 0; r < 8; ++r)
            #pragma unroll
            for (int c = 0; c < 4; ++c) acc[r][c] = 0.f;
        #pragma unroll 4
        for (int kk = 0; kk < 32; ++kk) {
            float4 b0 = W4[(tx * 4 + 0) * 32 + kk];
            float4 b1v = W4[(tx * 4 + 1) * 32 + kk];
            float4 b2v = W4[(tx * 4 + 2) * 32 + kk];
            float4 b3v = W4[(tx * 4 + 3) * 32 + kk];
            #pragma unroll
            for (int r = 0; r < 8; ++r) {
                float4 a = ((const float4*)&Hs[ty * 8 + r][0])[kk];
                acc[r][0] += a.x * b0.x + a.y * b0.y + a.z * b0.z + a.w * b0.w;
                acc[r][1] += a.x * b1v.x + a.y * b1v.y + a.z * b1v.z + a.w * b1v.w;
                acc[r][2] += a.x * b2v.x + a.y * b2v.y + a.z * b2v.z + a.w * b2v.w;
                acc[r][3] += a.x * b3v.x + a.y * b3v.y + a.z * b3v.z + a.w * b3v.w;
            }
        }
        float4 bias = ((const float4*)b2)[tx];
        #pragma unroll
        for (int r = 0; r < 8; ++r) {
            int row = row0 + ty * 8 + r;
            if (row < N_NODES) {
                float4 vv = ((const float4*)v)[row * 32 + tx];
                float4 o;
                o.x = vv.x + fmaxf(acc[r][0] + bias.x, 0.f);
                o.y = vv.y + fmaxf(acc[r][1] + bias.y, 0.f);
                o.z = vv.z + fmaxf(acc[r][2] + bias.z, 0.f);
                o.w = vv.w + fmaxf(acc[r][3] + bias.w, 0.f);
                ((float4*)out)[row * 32 + tx] = o;
            }
        }
    }
}

extern "C" void kernel_launch(void* const* d_in, const int* in_sizes, int n_in,
                              void* d_out, int out_size, void* d_ws, size_t ws_size,
                              hipStream_t stream) {
    const float* feats  = (const float*)d_in[0];
    const int*   idx_kj = (const int*)d_in[1];
    const int*   idx_ji = (const int*)d_in[2];
    const float* Wv     = (const float*)d_in[3];
    const float* Wq     = (const float*)d_in[4];
    const float* Wk     = (const float*)d_in[5];
    const float* W1     = (const float*)d_in[6];
    const float* b1     = (const float*)d_in[7];
    const float* W2     = (const float*)d_in[8];
    const float* b2     = (const float*)d_in[9];
    float* out = (float*)d_out;

    // workspace: q, k, v (fp32) then CSR arrays (int)
    float* ws = (float*)d_ws;
    float* q  = ws;
    float* k  = q + (size_t)N_NODES * HID;
    float* v  = k + (size_t)N_NODES * HID;
    int* count     = (int*)(v + (size_t)N_NODES * HID);
    int* offsets   = count + N_NODES;
    int* cursor    = offsets + N_NODES;
    int* edge_list = cursor + N_NODES;
    float* agg = out;   // aggregate writes every row; consumed in-place by mlp

    hipMemsetAsync(count, 0, N_NODES * sizeof(int), stream);

    qkv_kernel<<<(N_NODES + 63) / 64, 256, 0, stream>>>(feats, Wq, Wk, Wv, q, k, v);
    hist_kernel<<<(M_EDGES + 255) / 256, 256, 0, stream>>>(idx_ji, count);
    scan_kernel<<<1, 1024, 0, stream>>>(count, offsets, cursor);
    fill_kernel<<<(M_EDGES + 255) / 256, 256, 0, stream>>>(idx_ji, cursor, edge_list);
    aggregate_kernel<<<(N_NODES * 64 + 255) / 256, 256, 0, stream>>>(
        edge_list, offsets, count, idx_kj, q, k, v, agg);
    mlp_kernel<<<(N_NODES + 63) / 64, 256, 0, stream>>>(agg, v, W1, b1, W2, b2, out);
}

// Round 3
// 676.845 us; speedup vs baseline: 3.1926x; 1.7092x over previous
//
#include <hip/hip_runtime.h>
#include <hip/hip_bf16.h>
#include <math.h>

#define N_NODES 100000
#define M_EDGES 800000
#define HID 128
#define HEADS 8
#define DH 16

typedef __attribute__((ext_vector_type(8))) short short8;   // 8 x bf16 (4 VGPRs)
typedef __attribute__((ext_vector_type(4))) float floatx4;  // MFMA accumulator

__device__ __forceinline__ ushort f32_to_bf16(float x) {
    __hip_bfloat16 h = __float2bfloat16(x);   // RNE
    union { __hip_bfloat16 h; ushort u; } c; c.h = h;
    return c.u;
}
__device__ __forceinline__ float bf16_bits_to_f32(ushort u) {
    union { unsigned int i; float f; } c; c.i = ((unsigned int)u) << 16;
    return c.f;
}
__device__ __forceinline__ float bf16pair_lo(unsigned int p) {
    union { unsigned int i; float f; } c; c.i = p << 16; return c.f;
}
__device__ __forceinline__ float bf16pair_hi(unsigned int p) {
    union { unsigned int i; float f; } c; c.i = p & 0xffff0000u; return c.f;
}

// ---------------------------------------------------------------------------
// Convert feats (N x 128 fp32) -> bf16, vectorized x4.
// ---------------------------------------------------------------------------
__global__ __launch_bounds__(256) void cvt_feats_kernel(
    const float* __restrict__ src, ushort* __restrict__ dst)
{
    int i = (blockIdx.x * 256 + threadIdx.x) * 4;
    if (i >= N_NODES * HID) return;
    float4 f = *(const float4*)(src + i);
    ushort4 o;
    o.x = f32_to_bf16(f.x); o.y = f32_to_bf16(f.y);
    o.z = f32_to_bf16(f.z); o.w = f32_to_bf16(f.w);
    *(ushort4*)(dst + i) = o;
}

// Convert the five 128x128 weight matrices -> bf16 in one dispatch.
__global__ __launch_bounds__(256) void cvt_w_kernel(
    const float* __restrict__ Wq, const float* __restrict__ Wk, const float* __restrict__ Wv,
    const float* __restrict__ W1, const float* __restrict__ W2,
    ushort* __restrict__ dq, ushort* __restrict__ dk, ushort* __restrict__ dv,
    ushort* __restrict__ d1, ushort* __restrict__ d2)
{
    int i = blockIdx.x * 256 + threadIdx.x;        // 0 .. 5*16384-1
    int w = i >> 14;
    int j = i & 16383;
    const float* s[5] = {Wq, Wk, Wv, W1, W2};
    ushort*      d[5] = {dq, dk, dv, d1, d2};
    d[w][j] = f32_to_bf16(s[w][j]);
}

// ---------------------------------------------------------------------------
// Kernel: fused Q/K/V projection via bf16 MFMA.  4 waves/block, each wave
// computes 16 rows x 128 cols for all three matrices.  A-frag and B-frag are
// both contiguous 16B loads from row-major [*,128] bf16 matrices.
// Outputs bf16 (row-major), consumed by aggregate + mlp.
// ---------------------------------------------------------------------------
__global__ __launch_bounds__(256) void qkv_mfma_kernel(
    const ushort* __restrict__ feats16,
    const ushort* __restrict__ Wq16, const ushort* __restrict__ Wk16, const ushort* __restrict__ Wv16,
    ushort* __restrict__ q16, ushort* __restrict__ k16, ushort* __restrict__ v16)
{
    const int wave = threadIdx.x >> 6;
    const int lane = threadIdx.x & 63;
    const int row0 = blockIdx.x * 64 + wave * 16;       // N % 16 == 0
    const bool valid = (row0 < N_NODES);
    const int rbase = valid ? row0 : 0;
    const int lrow = lane & 15;
    const int lk   = (lane >> 4) * 8;

    // preload the 4 A fragments (K = 128 = 4 x 32), reused for all 3 matrices
    short8 afrag[4];
    const ushort* arow = feats16 + (size_t)(rbase + lrow) * HID + lk;
    #pragma unroll
    for (int ks = 0; ks < 4; ++ks)
        afrag[ks] = *(const short8*)(arow + ks * 32);

    const ushort* Ws[3] = {Wq16, Wk16, Wv16};
    ushort*       Os[3] = {q16, k16, v16};

    #pragma unroll
    for (int w = 0; w < 3; ++w) {
        floatx4 acc[8];
        #pragma unroll
        for (int t = 0; t < 8; ++t) acc[t] = (floatx4)(0.f);
        #pragma unroll
        for (int ks = 0; ks < 4; ++ks) {
            const ushort* wbase = Ws[w] + (size_t)lrow * HID + ks * 32 + lk;
            #pragma unroll
            for (int t = 0; t < 8; ++t) {
                short8 b = *(const short8*)(wbase + (size_t)t * 16 * HID);
                acc[t] = __builtin_amdgcn_mfma_f32_16x16x32_bf16(afrag[ks], b, acc[t], 0, 0, 0);
            }
        }
        if (valid) {
            const int orow = row0 + (lane >> 4) * 4;    // C/D: col=lane&15, row=quad*4+reg
            ushort* O = Os[w];
            #pragma unroll
            for (int t = 0; t < 8; ++t)
                #pragma unroll
                for (int r = 0; r < 4; ++r)
                    O[(size_t)(orow + r) * HID + t * 16 + lrow] = f32_to_bf16(acc[t][r]);
        }
    }
}

// ---------------------------------------------------------------------------
// CSR build: histogram, single-block scan, fill.
// ---------------------------------------------------------------------------
__global__ __launch_bounds__(256) void hist_kernel(
    const int* __restrict__ idx_ji, int* __restrict__ count)
{
    int m = blockIdx.x * 256 + threadIdx.x;
    if (m < M_EDGES) atomicAdd(&count[idx_ji[m]], 1);
}

__global__ __launch_bounds__(1024) void scan_kernel(
    const int* __restrict__ count, int* __restrict__ offsets, int* __restrict__ cursor)
{
    __shared__ int sdata[1024];
    const int t = threadIdx.x;
    const int CHUNK = (N_NODES + 1023) / 1024;
    const int start = t * CHUNK;
    const int end   = min(start + CHUNK, N_NODES);

    int partial = 0;
    for (int i = start; i < end; ++i) partial += count[i];
    sdata[t] = partial;
    __syncthreads();

    for (int off = 1; off < 1024; off <<= 1) {
        int val = (t >= off) ? sdata[t - off] : 0;
        __syncthreads();
        sdata[t] += val;
        __syncthreads();
    }

    int base = sdata[t] - partial;
    for (int i = start; i < end; ++i) {
        offsets[i] = base;
        cursor[i]  = base;
        base += count[i];
    }
}

__global__ __launch_bounds__(256) void fill_kernel(
    const int* __restrict__ idx_ji, int* __restrict__ cursor, int* __restrict__ edge_list)
{
    int m = blockIdx.x * 256 + threadIdx.x;
    if (m < M_EDGES) {
        int pos = atomicAdd(&cursor[idx_ji[m]], 1);
        edge_list[pos] = m;
    }
}

// ---------------------------------------------------------------------------
// Fused attention + normalized aggregation, gather-style, bf16 in/out.
// One wave per destination node; lane owns channels 2*lane, 2*lane+1
// (head = lane/8).  Scores via 3x shfl_xor in the 8-lane head group.
// fp32 accumulation; zero atomics; agg written in bf16 for the MFMA MLP.
// ---------------------------------------------------------------------------
__global__ __launch_bounds__(256) void aggregate_kernel(
    const int* __restrict__ edge_list, const int* __restrict__ offsets,
    const int* __restrict__ count, const int* __restrict__ idx_kj,
    const ushort* __restrict__ q16, const ushort* __restrict__ k16,
    const ushort* __restrict__ v16, ushort* __restrict__ agg16)
{
    int gid  = blockIdx.x * 256 + threadIdx.x;
    int node = gid >> 6;
    int lane = threadIdx.x & 63;
    if (node >= N_NODES) return;

    const int deg  = count[node];
    const int base = offsets[node];

    unsigned int knp = *(const unsigned int*)(k16 + (size_t)node * HID + lane * 2);
    const float knx = bf16pair_lo(knp), kny = bf16pair_hi(knp);
    float accx = 0.f, accy = 0.f, d = 0.f;

    int e = 0;
    for (; e + 2 <= deg; e += 2) {
        int m0 = edge_list[base + e];
        int m1 = edge_list[base + e + 1];
        int kj0 = idx_kj[m0];
        int kj1 = idx_kj[m1];
        unsigned int qp0 = *(const unsigned int*)(q16 + (size_t)kj0 * HID + lane * 2);
        unsigned int vp0 = *(const unsigned int*)(v16 + (size_t)kj0 * HID + lane * 2);
        unsigned int qp1 = *(const unsigned int*)(q16 + (size_t)kj1 * HID + lane * 2);
        unsigned int vp1 = *(const unsigned int*)(v16 + (size_t)kj1 * HID + lane * 2);

        float p0 = bf16pair_lo(qp0) * knx + bf16pair_hi(qp0) * kny;
        p0 += __shfl_xor(p0, 1); p0 += __shfl_xor(p0, 2); p0 += __shfl_xor(p0, 4);
        float s0 = (p0 >= 0.f) ? p0 : 0.2f * p0;
        s0 = expf(s0);
        d += s0;
        accx += s0 * bf16pair_lo(vp0);
        accy += s0 * bf16pair_hi(vp0);

        float p1 = bf16pair_lo(qp1) * knx + bf16pair_hi(qp1) * kny;
        p1 += __shfl_xor(p1, 1); p1 += __shfl_xor(p1, 2); p1 += __shfl_xor(p1, 4);
        float s1 = (p1 >= 0.f) ? p1 : 0.2f * p1;
        s1 = expf(s1);
        d += s1;
        accx += s1 * bf16pair_lo(vp1);
        accy += s1 * bf16pair_hi(vp1);
    }
    if (e < deg) {
        int m0 = edge_list[base + e];
        int kj0 = idx_kj[m0];
        unsigned int qp0 = *(const unsigned int*)(q16 + (size_t)kj0 * HID + lane * 2);
        unsigned int vp0 = *(const unsigned int*)(v16 + (size_t)kj0 * HID + lane * 2);
        float p0 = bf16pair_lo(qp0) * knx + bf16pair_hi(qp0) * kny;
        p0 += __shfl_xor(p0, 1); p0 += __shfl_xor(p0, 2); p0 += __shfl_xor(p0, 4);
        float s0 = (p0 >= 0.f) ? p0 : 0.2f * p0;
        s0 = expf(s0);
        d += s0;
        accx += s0 * bf16pair_lo(vp0);
        accy += s0 * bf16pair_hi(vp0);
    }

    const float inv = (deg > 0) ? 1.f / d : 0.f;     // deg==0 -> zeros, not NaN
    unsigned int outp = (unsigned int)f32_to_bf16(accx * inv)
                      | ((unsigned int)f32_to_bf16(accy * inv) << 16);
    *(unsigned int*)(agg16 + (size_t)node * HID + lane * 2) = outp;
}

// ---------------------------------------------------------------------------
// Residual MLP via bf16 MFMA.  out = v + relu(relu(agg@W1.T+b1)@W2.T+b2).
// h1 round-trips through LDS as bf16 in A-fragment layout.
// Row stride 152 ushorts (=304B): 16B-aligned rows + conflict-free b16 writes.
// ---------------------------------------------------------------------------
#define H1_STRIDE 152
__global__ __launch_bounds__(256) void mlp_mfma_kernel(
    const ushort* __restrict__ agg16, const ushort* __restrict__ v16,
    const ushort* __restrict__ W1_16, const float* __restrict__ b1,
    const ushort* __restrict__ W2_16, const float* __restrict__ b2,
    float* __restrict__ out)
{
    __shared__ ushort h1s[4][16][H1_STRIDE];
    const int wave = threadIdx.x >> 6;
    const int lane = threadIdx.x & 63;
    const int row0 = blockIdx.x * 64 + wave * 16;
    const bool valid = (row0 < N_NODES);
    const int rbase = valid ? row0 : 0;
    const int lrow = lane & 15;
    const int lk   = (lane >> 4) * 8;
    const int crow = (lane >> 4) * 4;

    // phase 1: h1 = relu(agg @ W1.T + b1)
    floatx4 acc[8];
    #pragma unroll
    for (int t = 0; t < 8; ++t) acc[t] = (floatx4)(0.f);
    {
        const ushort* arow = agg16 + (size_t)(rbase + lrow) * HID + lk;
        #pragma unroll
        for (int ks = 0; ks < 4; ++ks) {
            short8 a = *(const short8*)(arow + ks * 32);
            const ushort* wbase = W1_16 + (size_t)lrow * HID + ks * 32 + lk;
            #pragma unroll
            for (int t = 0; t < 8; ++t) {
                short8 b = *(const short8*)(wbase + (size_t)t * 16 * HID);
                acc[t] = __builtin_amdgcn_mfma_f32_16x16x32_bf16(a, b, acc[t], 0, 0, 0);
            }
        }
    }
    #pragma unroll
    for (int t = 0; t < 8; ++t) {
        float bias = b1[t * 16 + lrow];
        #pragma unroll
        for (int r = 0; r < 4; ++r)
            h1s[wave][crow + r][t * 16 + lrow] = f32_to_bf16(fmaxf(acc[t][r] + bias, 0.f));
    }
    __syncthreads();   // all 256 threads reach this (no early returns)

    // phase 2: h2 = relu(h1 @ W2.T + b2); out = v + h2
    #pragma unroll
    for (int t = 0; t < 8; ++t) acc[t] = (floatx4)(0.f);
    #pragma unroll
    for (int ks = 0; ks < 4; ++ks) {
        short8 a = *(const short8*)&h1s[wave][lrow][ks * 32 + lk];
        const ushort* wbase = W2_16 + (size_t)lrow * HID + ks * 32 + lk;
        #pragma unroll
        for (int t = 0; t < 8; ++t) {
            short8 b = *(const short8*)(wbase + (size_t)t * 16 * HID);
            acc[t] = __builtin_amdgcn_mfma_f32_16x16x32_bf16(a, b, acc[t], 0, 0, 0);
        }
    }
    if (valid) {
        #pragma unroll
        for (int t = 0; t < 8; ++t) {
            float bias = b2[t * 16 + lrow];
            #pragma unroll
            for (int r = 0; r < 4; ++r) {
                size_t off = (size_t)(row0 + crow + r) * HID + t * 16 + lrow;
                float vv = bf16_bits_to_f32(v16[off]);
                out[off] = vv + fmaxf(acc[t][r] + bias, 0.f);
            }
        }
    }
}

extern "C" void kernel_launch(void* const* d_in, const int* in_sizes, int n_in,
                              void* d_out, int out_size, void* d_ws, size_t ws_size,
                              hipStream_t stream) {
    const float* feats  = (const float*)d_in[0];
    const int*   idx_kj = (const int*)d_in[1];
    const int*   idx_ji = (const int*)d_in[2];
    const float* Wv     = (const float*)d_in[3];
    const float* Wq     = (const float*)d_in[4];
    const float* Wk     = (const float*)d_in[5];
    const float* W1     = (const float*)d_in[6];
    const float* b1     = (const float*)d_in[7];
    const float* W2     = (const float*)d_in[8];
    const float* b2     = (const float*)d_in[9];
    float* out = (float*)d_out;

    // workspace layout (bf16 arrays first, all 16B-aligned sizes)
    ushort* feats16 = (ushort*)d_ws;
    ushort* q16     = feats16 + (size_t)N_NODES * HID;
    ushort* k16     = q16     + (size_t)N_NODES * HID;
    ushort* v16     = k16     + (size_t)N_NODES * HID;
    ushort* agg16   = v16     + (size_t)N_NODES * HID;
    ushort* Wq16    = agg16   + (size_t)N_NODES * HID;
    ushort* Wk16    = Wq16 + HID * HID;
    ushort* Wv16    = Wk16 + HID * HID;
    ushort* W116    = Wv16 + HID * HID;
    ushort* W216    = W116 + HID * HID;
    int* count      = (int*)(W216 + HID * HID);
    int* offsets    = count + N_NODES;
    int* cursor     = offsets + N_NODES;
    int* edge_list  = cursor + N_NODES;

    hipMemsetAsync(count, 0, N_NODES * sizeof(int), stream);

    cvt_feats_kernel<<<(N_NODES * HID / 4 + 255) / 256, 256, 0, stream>>>(feats, feats16);
    cvt_w_kernel<<<(5 * HID * HID + 255) / 256, 256, 0, stream>>>(
        Wq, Wk, Wv, W1, W2, Wq16, Wk16, Wv16, W116, W216);

    qkv_mfma_kernel<<<(N_NODES + 63) / 64, 256, 0, stream>>>(
        feats16, Wq16, Wk16, Wv16, q16, k16, v16);

    hist_kernel<<<(M_EDGES + 255) / 256, 256, 0, stream>>>(idx_ji, count);
    scan_kernel<<<1, 1024, 0, stream>>>(count, offsets, cursor);
    fill_kernel<<<(M_EDGES + 255) / 256, 256, 0, stream>>>(idx_ji, cursor, edge_list);

    aggregate_kernel<<<(N_NODES * 64 + 255) / 256, 256, 0, stream>>>(
        edge_list, offsets, count, idx_kj, q16, k16, v16, agg16);

    mlp_mfma_kernel<<<(N_NODES + 63) / 64, 256, 0, stream>>>(
        agg16, v16, W116, b1, W216, b2, out);
}

// Round 4
// 418.525 us; speedup vs baseline: 5.1631x; 1.6172x over previous
//
#include <hip/hip_runtime.h>
#include <hip/hip_bf16.h>
#include <math.h>

#define N_NODES 100000
#define M_EDGES 800000
#define HID 128
#define HEADS 8
#define DH 16
#define SCAN_NB ((N_NODES + 1023) / 1024)   // 98 blocks of 1024 counts

typedef __attribute__((ext_vector_type(8))) short short8;   // 8 x bf16 (4 VGPRs)
typedef __attribute__((ext_vector_type(4))) float floatx4;  // MFMA accumulator

__device__ __forceinline__ ushort f32_to_bf16(float x) {
    __hip_bfloat16 h = __float2bfloat16(x);   // RNE
    union { __hip_bfloat16 h; ushort u; } c; c.h = h;
    return c.u;
}
__device__ __forceinline__ float bf16_bits_to_f32(ushort u) {
    union { unsigned int i; float f; } c; c.i = ((unsigned int)u) << 16;
    return c.f;
}
__device__ __forceinline__ float bf16pair_lo(unsigned int p) {
    union { unsigned int i; float f; } c; c.i = p << 16; return c.f;
}
__device__ __forceinline__ float bf16pair_hi(unsigned int p) {
    union { unsigned int i; float f; } c; c.i = p & 0xffff0000u; return c.f;
}

// ---------------------------------------------------------------------------
// Convert the five 128x128 weight matrices -> bf16 in one dispatch.
// ---------------------------------------------------------------------------
__global__ __launch_bounds__(256) void cvt_w_kernel(
    const float* __restrict__ Wq, const float* __restrict__ Wk, const float* __restrict__ Wv,
    const float* __restrict__ W1, const float* __restrict__ W2,
    ushort* __restrict__ dq, ushort* __restrict__ dk, ushort* __restrict__ dv,
    ushort* __restrict__ d1, ushort* __restrict__ d2)
{
    int i = blockIdx.x * 256 + threadIdx.x;        // 0 .. 5*16384-1
    int w = i >> 14;
    int j = i & 16383;
    const float* s[5] = {Wq, Wk, Wv, W1, W2};
    ushort*      d[5] = {dq, dk, dv, d1, d2};
    d[w][j] = f32_to_bf16(s[w][j]);
}

// ---------------------------------------------------------------------------
// Fused Q/K/V projection via bf16 MFMA, converting feats fp32->bf16 in-reg.
// 4 waves/block, each wave computes 16 rows x 128 cols for all three W.
// ---------------------------------------------------------------------------
__global__ __launch_bounds__(256) void qkv_mfma_kernel(
    const float* __restrict__ feats,
    const ushort* __restrict__ Wq16, const ushort* __restrict__ Wk16, const ushort* __restrict__ Wv16,
    ushort* __restrict__ q16, ushort* __restrict__ k16, ushort* __restrict__ v16)
{
    const int wave = threadIdx.x >> 6;
    const int lane = threadIdx.x & 63;
    const int row0 = blockIdx.x * 64 + wave * 16;       // N % 16 == 0
    const bool valid = (row0 < N_NODES);
    const int rbase = valid ? row0 : 0;
    const int lrow = lane & 15;
    const int lk   = (lane >> 4) * 8;

    // preload the 4 A fragments (K = 128 = 4 x 32), converting fp32->bf16
    short8 afrag[4];
    const float* arow = feats + (size_t)(rbase + lrow) * HID + lk;
    #pragma unroll
    for (int ks = 0; ks < 4; ++ks) {
        float4 f0 = *(const float4*)(arow + ks * 32);
        float4 f1 = *(const float4*)(arow + ks * 32 + 4);
        short8 a;
        a[0] = (short)f32_to_bf16(f0.x); a[1] = (short)f32_to_bf16(f0.y);
        a[2] = (short)f32_to_bf16(f0.z); a[3] = (short)f32_to_bf16(f0.w);
        a[4] = (short)f32_to_bf16(f1.x); a[5] = (short)f32_to_bf16(f1.y);
        a[6] = (short)f32_to_bf16(f1.z); a[7] = (short)f32_to_bf16(f1.w);
        afrag[ks] = a;
    }

    const ushort* Ws[3] = {Wq16, Wk16, Wv16};
    ushort*       Os[3] = {q16, k16, v16};

    #pragma unroll
    for (int w = 0; w < 3; ++w) {
        floatx4 acc[8];
        #pragma unroll
        for (int t = 0; t < 8; ++t) acc[t] = (floatx4)(0.f);
        #pragma unroll
        for (int ks = 0; ks < 4; ++ks) {
            const ushort* wbase = Ws[w] + (size_t)lrow * HID + ks * 32 + lk;
            #pragma unroll
            for (int t = 0; t < 8; ++t) {
                short8 b = *(const short8*)(wbase + (size_t)t * 16 * HID);
                acc[t] = __builtin_amdgcn_mfma_f32_16x16x32_bf16(afrag[ks], b, acc[t], 0, 0, 0);
            }
        }
        if (valid) {
            const int orow = row0 + (lane >> 4) * 4;    // C/D: col=lane&15, row=quad*4+reg
            ushort* O = Os[w];
            #pragma unroll
            for (int t = 0; t < 8; ++t)
                #pragma unroll
                for (int r = 0; r < 4; ++r)
                    O[(size_t)(orow + r) * HID + t * 16 + lrow] = f32_to_bf16(acc[t][r]);
        }
    }
}

// ---------------------------------------------------------------------------
// CSR build: histogram -> 3-stage device-wide scan -> fill (stores kj direct).
// ---------------------------------------------------------------------------
__global__ __launch_bounds__(256) void hist_kernel(
    const int* __restrict__ idx_ji, int* __restrict__ count)
{
    int m = blockIdx.x * 256 + threadIdx.x;
    if (m < M_EDGES) atomicAdd(&count[idx_ji[m]], 1);
}

// Stage A: per-block (1024 counts) sums.
__global__ __launch_bounds__(256) void scan_blocksum_kernel(
    const int* __restrict__ count, int* __restrict__ blocksum)
{
    __shared__ int s[256];
    const int tid = threadIdx.x;
    const int base = blockIdx.x * 1024 + tid * 4;
    int sum = 0;
    if (base + 3 < N_NODES) {
        int4 c = *(const int4*)(count + base);
        sum = c.x + c.y + c.z + c.w;
    } else {
        #pragma unroll
        for (int j = 0; j < 4; ++j) if (base + j < N_NODES) sum += count[base + j];
    }
    s[tid] = sum;
    __syncthreads();
    for (int off = 128; off > 0; off >>= 1) {
        if (tid < off) s[tid] += s[tid + off];
        __syncthreads();
    }
    if (tid == 0) blocksum[blockIdx.x] = s[0];
}

// Stage B: exclusive scan of the SCAN_NB block sums (single tiny block).
__global__ __launch_bounds__(128) void scan_top_kernel(int* __restrict__ blocksum)
{
    __shared__ int s[128];
    const int t = threadIdx.x;
    int v = (t < SCAN_NB) ? blocksum[t] : 0;
    s[t] = v;
    __syncthreads();
    for (int off = 1; off < 128; off <<= 1) {
        int x = (t >= off) ? s[t - off] : 0;
        __syncthreads();
        s[t] += x;
        __syncthreads();
    }
    if (t < SCAN_NB) blocksum[t] = s[t] - v;   // exclusive
}

// Stage C: write offsets + cursor.
__global__ __launch_bounds__(256) void scan_write_kernel(
    const int* __restrict__ count, const int* __restrict__ blocksum,
    int* __restrict__ offsets, int* __restrict__ cursor)
{
    __shared__ int s[256];
    const int tid = threadIdx.x;
    const int base = blockIdx.x * 1024 + tid * 4;
    int c0 = 0, c1 = 0, c2 = 0, c3 = 0;
    if (base + 3 < N_NODES) {
        int4 c = *(const int4*)(count + base);
        c0 = c.x; c1 = c.y; c2 = c.z; c3 = c.w;
    } else {
        if (base     < N_NODES) c0 = count[base];
        if (base + 1 < N_NODES) c1 = count[base + 1];
        if (base + 2 < N_NODES) c2 = count[base + 2];
        if (base + 3 < N_NODES) c3 = count[base + 3];
    }
    const int tsum = c0 + c1 + c2 + c3;
    s[tid] = tsum;
    __syncthreads();
    for (int off = 1; off < 256; off <<= 1) {
        int x = (tid >= off) ? s[tid - off] : 0;
        __syncthreads();
        s[tid] += x;
        __syncthreads();
    }
    int o0 = s[tid] - tsum + blocksum[blockIdx.x];
    int o1 = o0 + c0, o2 = o1 + c1, o3 = o2 + c2;
    if (base + 3 < N_NODES) {
        *(int4*)(offsets + base) = make_int4(o0, o1, o2, o3);
        *(int4*)(cursor  + base) = make_int4(o0, o1, o2, o3);
    } else {
        if (base     < N_NODES) { offsets[base]     = o0; cursor[base]     = o0; }
        if (base + 1 < N_NODES) { offsets[base + 1] = o1; cursor[base + 1] = o1; }
        if (base + 2 < N_NODES) { offsets[base + 2] = o2; cursor[base + 2] = o2; }
        if (base + 3 < N_NODES) { offsets[base + 3] = o3; cursor[base + 3] = o3; }
    }
}

// Fill: store the SOURCE index (kj) directly — kills one indirection in the
// hot aggregate loop.
__global__ __launch_bounds__(256) void fill_kernel(
    const int* __restrict__ idx_ji, const int* __restrict__ idx_kj,
    int* __restrict__ cursor, int* __restrict__ edge_kj)
{
    int m = blockIdx.x * 256 + threadIdx.x;
    if (m < M_EDGES) {
        int pos = atomicAdd(&cursor[idx_ji[m]], 1);
        edge_kj[pos] = idx_kj[m];
    }
}

// ---------------------------------------------------------------------------
// Fused attention + normalized aggregation, gather-style, bf16 in/out.
// One wave per destination node; lane owns channels 2*lane, 2*lane+1
// (head = lane/8).  Scores via 3x shfl_xor in the 8-lane head group.
// fp32 accumulation; zero atomics; agg written in bf16 for the MFMA MLP.
// ---------------------------------------------------------------------------
__global__ __launch_bounds__(256) void aggregate_kernel(
    const int* __restrict__ edge_kj, const int* __restrict__ offsets,
    const int* __restrict__ count, const ushort* __restrict__ q16,
    const ushort* __restrict__ k16, const ushort* __restrict__ v16,
    ushort* __restrict__ agg16)
{
    int gid  = blockIdx.x * 256 + threadIdx.x;
    int node = gid >> 6;
    int lane = threadIdx.x & 63;
    if (node >= N_NODES) return;

    const int deg  = count[node];
    const int base = offsets[node];

    unsigned int knp = *(const unsigned int*)(k16 + (size_t)node * HID + lane * 2);
    const float knx = bf16pair_lo(knp), kny = bf16pair_hi(knp);
    float accx = 0.f, accy = 0.f, d = 0.f;

    int e = 0;
    for (; e + 2 <= deg; e += 2) {
        int kj0 = edge_kj[base + e];
        int kj1 = edge_kj[base + e + 1];
        unsigned int qp0 = *(const unsigned int*)(q16 + (size_t)kj0 * HID + lane * 2);
        unsigned int vp0 = *(const unsigned int*)(v16 + (size_t)kj0 * HID + lane * 2);
        unsigned int qp1 = *(const unsigned int*)(q16 + (size_t)kj1 * HID + lane * 2);
        unsigned int vp1 = *(const unsigned int*)(v16 + (size_t)kj1 * HID + lane * 2);

        float p0 = bf16pair_lo(qp0) * knx + bf16pair_hi(qp0) * kny;
        p0 += __shfl_xor(p0, 1); p0 += __shfl_xor(p0, 2); p0 += __shfl_xor(p0, 4);
        float s0 = (p0 >= 0.f) ? p0 : 0.2f * p0;
        s0 = expf(s0);
        d += s0;
        accx += s0 * bf16pair_lo(vp0);
        accy += s0 * bf16pair_hi(vp0);

        float p1 = bf16pair_lo(qp1) * knx + bf16pair_hi(qp1) * kny;
        p1 += __shfl_xor(p1, 1); p1 += __shfl_xor(p1, 2); p1 += __shfl_xor(p1, 4);
        float s1 = (p1 >= 0.f) ? p1 : 0.2f * p1;
        s1 = expf(s1);
        d += s1;
        accx += s1 * bf16pair_lo(vp1);
        accy += s1 * bf16pair_hi(vp1);
    }
    if (e < deg) {
        int kj0 = edge_kj[base + e];
        unsigned int qp0 = *(const unsigned int*)(q16 + (size_t)kj0 * HID + lane * 2);
        unsigned int vp0 = *(const unsigned int*)(v16 + (size_t)kj0 * HID + lane * 2);
        float p0 = bf16pair_lo(qp0) * knx + bf16pair_hi(qp0) * kny;
        p0 += __shfl_xor(p0, 1); p0 += __shfl_xor(p0, 2); p0 += __shfl_xor(p0, 4);
        float s0 = (p0 >= 0.f) ? p0 : 0.2f * p0;
        s0 = expf(s0);
        d += s0;
        accx += s0 * bf16pair_lo(vp0);
        accy += s0 * bf16pair_hi(vp0);
    }

    const float inv = (deg > 0) ? 1.f / d : 0.f;     // deg==0 -> zeros, not NaN
    unsigned int outp = (unsigned int)f32_to_bf16(accx * inv)
                      | ((unsigned int)f32_to_bf16(accy * inv) << 16);
    *(unsigned int*)(agg16 + (size_t)node * HID + lane * 2) = outp;
}

// ---------------------------------------------------------------------------
// Residual MLP via bf16 MFMA.  out = v + relu(relu(agg@W1.T+b1)@W2.T+b2).
// h1 round-trips through LDS as bf16 in A-fragment layout.
// ---------------------------------------------------------------------------
#define H1_STRIDE 152
__global__ __launch_bounds__(256) void mlp_mfma_kernel(
    const ushort* __restrict__ agg16, const ushort* __restrict__ v16,
    const ushort* __restrict__ W1_16, const float* __restrict__ b1,
    const ushort* __restrict__ W2_16, const float* __restrict__ b2,
    float* __restrict__ out)
{
    __shared__ ushort h1s[4][16][H1_STRIDE];
    const int wave = threadIdx.x >> 6;
    const int lane = threadIdx.x & 63;
    const int row0 = blockIdx.x * 64 + wave * 16;
    const bool valid = (row0 < N_NODES);
    const int rbase = valid ? row0 : 0;
    const int lrow = lane & 15;
    const int lk   = (lane >> 4) * 8;
    const int crow = (lane >> 4) * 4;

    // phase 1: h1 = relu(agg @ W1.T + b1)
    floatx4 acc[8];
    #pragma unroll
    for (int t = 0; t < 8; ++t) acc[t] = (floatx4)(0.f);
    {
        const ushort* arow = agg16 + (size_t)(rbase + lrow) * HID + lk;
        #pragma unroll
        for (int ks = 0; ks < 4; ++ks) {
            short8 a = *(const short8*)(arow + ks * 32);
            const ushort* wbase = W1_16 + (size_t)lrow * HID + ks * 32 + lk;
            #pragma unroll
            for (int t = 0; t < 8; ++t) {
                short8 b = *(const short8*)(wbase + (size_t)t * 16 * HID);
                acc[t] = __builtin_amdgcn_mfma_f32_16x16x32_bf16(a, b, acc[t], 0, 0, 0);
            }
        }
    }
    #pragma unroll
    for (int t = 0; t < 8; ++t) {
        float bias = b1[t * 16 + lrow];
        #pragma unroll
        for (int r = 0; r < 4; ++r)
            h1s[wave][crow + r][t * 16 + lrow] = f32_to_bf16(fmaxf(acc[t][r] + bias, 0.f));
    }
    __syncthreads();   // all 256 threads reach this (no early returns)

    // phase 2: h2 = relu(h1 @ W2.T + b2); out = v + h2
    #pragma unroll
    for (int t = 0; t < 8; ++t) acc[t] = (floatx4)(0.f);
    #pragma unroll
    for (int ks = 0; ks < 4; ++ks) {
        short8 a = *(const short8*)&h1s[wave][lrow][ks * 32 + lk];
        const ushort* wbase = W2_16 + (size_t)lrow * HID + ks * 32 + lk;
        #pragma unroll
        for (int t = 0; t < 8; ++t) {
            short8 b = *(const short8*)(wbase + (size_t)t * 16 * HID);
            acc[t] = __builtin_amdgcn_mfma_f32_16x16x32_bf16(a, b, acc[t], 0, 0, 0);
        }
    }
    if (valid) {
        #pragma unroll
        for (int t = 0; t < 8; ++t) {
            float bias = b2[t * 16 + lrow];
            #pragma unroll
            for (int r = 0; r < 4; ++r) {
                size_t off = (size_t)(row0 + crow + r) * HID + t * 16 + lrow;
                float vv = bf16_bits_to_f32(v16[off]);
                out[off] = vv + fmaxf(acc[t][r] + bias, 0.f);
            }
        }
    }
}

extern "C" void kernel_launch(void* const* d_in, const int* in_sizes, int n_in,
                              void* d_out, int out_size, void* d_ws, size_t ws_size,
                              hipStream_t stream) {
    const float* feats  = (const float*)d_in[0];
    const int*   idx_kj = (const int*)d_in[1];
    const int*   idx_ji = (const int*)d_in[2];
    const float* Wv     = (const float*)d_in[3];
    const float* Wq     = (const float*)d_in[4];
    const float* Wk     = (const float*)d_in[5];
    const float* W1     = (const float*)d_in[6];
    const float* b1     = (const float*)d_in[7];
    const float* W2     = (const float*)d_in[8];
    const float* b2     = (const float*)d_in[9];
    float* out = (float*)d_out;

    // workspace layout (bf16 arrays first, all 16B-aligned sizes)
    ushort* q16     = (ushort*)d_ws;
    ushort* k16     = q16     + (size_t)N_NODES * HID;
    ushort* v16     = k16     + (size_t)N_NODES * HID;
    ushort* agg16   = v16     + (size_t)N_NODES * HID;
    ushort* Wq16    = agg16   + (size_t)N_NODES * HID;
    ushort* Wk16    = Wq16 + HID * HID;
    ushort* Wv16    = Wk16 + HID * HID;
    ushort* W116    = Wv16 + HID * HID;
    ushort* W216    = W116 + HID * HID;
    int* count      = (int*)(W216 + HID * HID);
    int* offsets    = count + N_NODES;
    int* cursor     = offsets + N_NODES;
    int* blocksum   = cursor + N_NODES;
    int* edge_kj    = blocksum + ((SCAN_NB + 3) & ~3);

    hipMemsetAsync(count, 0, N_NODES * sizeof(int), stream);

    cvt_w_kernel<<<(5 * HID * HID + 255) / 256, 256, 0, stream>>>(
        Wq, Wk, Wv, W1, W2, Wq16, Wk16, Wv16, W116, W216);

    qkv_mfma_kernel<<<(N_NODES + 63) / 64, 256, 0, stream>>>(
        feats, Wq16, Wk16, Wv16, q16, k16, v16);

    hist_kernel<<<(M_EDGES + 255) / 256, 256, 0, stream>>>(idx_ji, count);
    scan_blocksum_kernel<<<SCAN_NB, 256, 0, stream>>>(count, blocksum);
    scan_top_kernel<<<1, 128, 0, stream>>>(blocksum);
    scan_write_kernel<<<SCAN_NB, 256, 0, stream>>>(count, blocksum, offsets, cursor);
    fill_kernel<<<(M_EDGES + 255) / 256, 256, 0, stream>>>(idx_ji, idx_kj, cursor, edge_kj);

    aggregate_kernel<<<(N_NODES * 64 + 255) / 256, 256, 0, stream>>>(
        edge_kj, offsets, count, q16, k16, v16, agg16);

    mlp_mfma_kernel<<<(N_NODES + 63) / 64, 256, 0, stream>>>(
        agg16, v16, W116, b1, W216, b2, out);
}

// Round 5
// 411.927 us; speedup vs baseline: 5.2458x; 1.0160x over previous
//
#include <hip/hip_runtime.h>
#include <hip/hip_bf16.h>
#include <math.h>

#define N_NODES 100000
#define M_EDGES 800000
#define HID 128
#define HEADS 8
#define DH 16
#define SCAN_NB ((N_NODES + 1023) / 1024)   // 98 blocks of 1024 counts

typedef __attribute__((ext_vector_type(8))) short short8;   // 8 x bf16 (4 VGPRs)
typedef __attribute__((ext_vector_type(4))) float floatx4;  // MFMA accumulator

__device__ __forceinline__ ushort f32_to_bf16(float x) {
    __hip_bfloat16 h = __float2bfloat16(x);   // RNE
    union { __hip_bfloat16 h; ushort u; } c; c.h = h;
    return c.u;
}
__device__ __forceinline__ float bf16_bits_to_f32(ushort u) {
    union { unsigned int i; float f; } c; c.i = ((unsigned int)u) << 16;
    return c.f;
}
__device__ __forceinline__ float bf16pair_lo(unsigned int p) {
    union { unsigned int i; float f; } c; c.i = p << 16; return c.f;
}
__device__ __forceinline__ float bf16pair_hi(unsigned int p) {
    union { unsigned int i; float f; } c; c.i = p & 0xffff0000u; return c.f;
}

// ---------------------------------------------------------------------------
// Convert the five 128x128 weight matrices -> bf16 in one dispatch.
// ---------------------------------------------------------------------------
__global__ __launch_bounds__(256) void cvt_w_kernel(
    const float* __restrict__ Wq, const float* __restrict__ Wk, const float* __restrict__ Wv,
    const float* __restrict__ W1, const float* __restrict__ W2,
    ushort* __restrict__ dq, ushort* __restrict__ dk, ushort* __restrict__ dv,
    ushort* __restrict__ d1, ushort* __restrict__ d2)
{
    int i = blockIdx.x * 256 + threadIdx.x;        // 0 .. 5*16384-1
    int w = i >> 14;
    int j = i & 16383;
    const float* s[5] = {Wq, Wk, Wv, W1, W2};
    ushort*      d[5] = {dq, dk, dv, d1, d2};
    d[w][j] = f32_to_bf16(s[w][j]);
}

// ---------------------------------------------------------------------------
// Fused Q/K/V projection via bf16 MFMA.  OPERAND-SWAPPED: builtin(Wfrag,
// featsfrag) transposes D so each lane holds 4 CONSECUTIVE channels
// (t*16+quad*4+r) of one node row (lane&15) -> packed ushort4 stores.
// 4 waves/block, 16 rows/wave, feats converted fp32->bf16 in-reg.
// ---------------------------------------------------------------------------
__global__ __launch_bounds__(256) void qkv_mfma_kernel(
    const float* __restrict__ feats,
    const ushort* __restrict__ Wq16, const ushort* __restrict__ Wk16, const ushort* __restrict__ Wv16,
    ushort* __restrict__ q16, ushort* __restrict__ k16, ushort* __restrict__ v16)
{
    const int wave = threadIdx.x >> 6;
    const int lane = threadIdx.x & 63;
    const int row0 = blockIdx.x * 64 + wave * 16;       // N % 16 == 0
    const bool valid = (row0 < N_NODES);
    const int rbase = valid ? row0 : 0;
    const int lrow = lane & 15;
    const int lk   = (lane >> 4) * 8;
    const int crow = (lane >> 4) * 4;

    // feats fragments (second MFMA operand), K = 128 = 4 x 32
    short8 ffrag[4];
    const float* arow = feats + (size_t)(rbase + lrow) * HID + lk;
    #pragma unroll
    for (int ks = 0; ks < 4; ++ks) {
        float4 f0 = *(const float4*)(arow + ks * 32);
        float4 f1 = *(const float4*)(arow + ks * 32 + 4);
        short8 a;
        a[0] = (short)f32_to_bf16(f0.x); a[1] = (short)f32_to_bf16(f0.y);
        a[2] = (short)f32_to_bf16(f0.z); a[3] = (short)f32_to_bf16(f0.w);
        a[4] = (short)f32_to_bf16(f1.x); a[5] = (short)f32_to_bf16(f1.y);
        a[6] = (short)f32_to_bf16(f1.z); a[7] = (short)f32_to_bf16(f1.w);
        ffrag[ks] = a;
    }

    const ushort* Ws[3] = {Wq16, Wk16, Wv16};
    ushort*       Os[3] = {q16, k16, v16};

    #pragma unroll
    for (int w = 0; w < 3; ++w) {
        floatx4 acc[8];
        #pragma unroll
        for (int t = 0; t < 8; ++t) acc[t] = (floatx4)(0.f);
        #pragma unroll
        for (int ks = 0; ks < 4; ++ks) {
            const ushort* wbase = Ws[w] + (size_t)lrow * HID + ks * 32 + lk;
            #pragma unroll
            for (int t = 0; t < 8; ++t) {
                short8 b = *(const short8*)(wbase + (size_t)t * 16 * HID);
                // swapped: W first -> D rows = channels, D cols = nodes
                acc[t] = __builtin_amdgcn_mfma_f32_16x16x32_bf16(b, ffrag[ks], acc[t], 0, 0, 0);
            }
        }
        if (valid) {
            ushort* O = Os[w] + (size_t)(row0 + lrow) * HID;
            #pragma unroll
            for (int t = 0; t < 8; ++t) {
                ushort4 o;
                o.x = f32_to_bf16(acc[t][0]); o.y = f32_to_bf16(acc[t][1]);
                o.z = f32_to_bf16(acc[t][2]); o.w = f32_to_bf16(acc[t][3]);
                *(ushort4*)(O + t * 16 + crow) = o;
            }
        }
    }
}

// ---------------------------------------------------------------------------
// CSR build: histogram -> 3-stage device-wide scan -> fill (stores kj direct).
// ---------------------------------------------------------------------------
__global__ __launch_bounds__(256) void hist_kernel(
    const int* __restrict__ idx_ji, int* __restrict__ count)
{
    int m = blockIdx.x * 256 + threadIdx.x;
    if (m < M_EDGES) atomicAdd(&count[idx_ji[m]], 1);
}

__global__ __launch_bounds__(256) void scan_blocksum_kernel(
    const int* __restrict__ count, int* __restrict__ blocksum)
{
    __shared__ int s[256];
    const int tid = threadIdx.x;
    const int base = blockIdx.x * 1024 + tid * 4;
    int sum = 0;
    if (base + 3 < N_NODES) {
        int4 c = *(const int4*)(count + base);
        sum = c.x + c.y + c.z + c.w;
    } else {
        #pragma unroll
        for (int j = 0; j < 4; ++j) if (base + j < N_NODES) sum += count[base + j];
    }
    s[tid] = sum;
    __syncthreads();
    for (int off = 128; off > 0; off >>= 1) {
        if (tid < off) s[tid] += s[tid + off];
        __syncthreads();
    }
    if (tid == 0) blocksum[blockIdx.x] = s[0];
}

__global__ __launch_bounds__(128) void scan_top_kernel(int* __restrict__ blocksum)
{
    __shared__ int s[128];
    const int t = threadIdx.x;
    int v = (t < SCAN_NB) ? blocksum[t] : 0;
    s[t] = v;
    __syncthreads();
    for (int off = 1; off < 128; off <<= 1) {
        int x = (t >= off) ? s[t - off] : 0;
        __syncthreads();
        s[t] += x;
        __syncthreads();
    }
    if (t < SCAN_NB) blocksum[t] = s[t] - v;   // exclusive
}

__global__ __launch_bounds__(256) void scan_write_kernel(
    const int* __restrict__ count, const int* __restrict__ blocksum,
    int* __restrict__ offsets, int* __restrict__ cursor)
{
    __shared__ int s[256];
    const int tid = threadIdx.x;
    const int base = blockIdx.x * 1024 + tid * 4;
    int c0 = 0, c1 = 0, c2 = 0, c3 = 0;
    if (base + 3 < N_NODES) {
        int4 c = *(const int4*)(count + base);
        c0 = c.x; c1 = c.y; c2 = c.z; c3 = c.w;
    } else {
        if (base     < N_NODES) c0 = count[base];
        if (base + 1 < N_NODES) c1 = count[base + 1];
        if (base + 2 < N_NODES) c2 = count[base + 2];
        if (base + 3 < N_NODES) c3 = count[base + 3];
    }
    const int tsum = c0 + c1 + c2 + c3;
    s[tid] = tsum;
    __syncthreads();
    for (int off = 1; off < 256; off <<= 1) {
        int x = (tid >= off) ? s[tid - off] : 0;
        __syncthreads();
        s[tid] += x;
        __syncthreads();
    }
    int o0 = s[tid] - tsum + blocksum[blockIdx.x];
    int o1 = o0 + c0, o2 = o1 + c1, o3 = o2 + c2;
    if (base + 3 < N_NODES) {
        *(int4*)(offsets + base) = make_int4(o0, o1, o2, o3);
        *(int4*)(cursor  + base) = make_int4(o0, o1, o2, o3);
    } else {
        if (base     < N_NODES) { offsets[base]     = o0; cursor[base]     = o0; }
        if (base + 1 < N_NODES) { offsets[base + 1] = o1; cursor[base + 1] = o1; }
        if (base + 2 < N_NODES) { offsets[base + 2] = o2; cursor[base + 2] = o2; }
        if (base + 3 < N_NODES) { offsets[base + 3] = o3; cursor[base + 3] = o3; }
    }
}

__global__ __launch_bounds__(256) void fill_kernel(
    const int* __restrict__ idx_ji, const int* __restrict__ idx_kj,
    int* __restrict__ cursor, int* __restrict__ edge_kj)
{
    int m = blockIdx.x * 256 + threadIdx.x;
    if (m < M_EDGES) {
        int pos = atomicAdd(&cursor[idx_ji[m]], 1);
        edge_kj[pos] = idx_kj[m];
    }
}

// ---------------------------------------------------------------------------
// Fused attention + normalized aggregation, gather-style, bf16 in/out.
// One wave per destination node; lane owns channels 2*lane, 2*lane+1
// (head = lane/8).  4-edge unroll: 8 independent row-gathers in flight,
// 4 independent shfl reduction chains.  fp32 accumulation; zero atomics.
// ---------------------------------------------------------------------------
__global__ __launch_bounds__(256) void aggregate_kernel(
    const int* __restrict__ edge_kj, const int* __restrict__ offsets,
    const int* __restrict__ count, const ushort* __restrict__ q16,
    const ushort* __restrict__ k16, const ushort* __restrict__ v16,
    ushort* __restrict__ agg16)
{
    int gid  = blockIdx.x * 256 + threadIdx.x;
    int node = gid >> 6;
    int lane = threadIdx.x & 63;
    if (node >= N_NODES) return;

    const int deg  = count[node];
    const int base = offsets[node];

    unsigned int knp = *(const unsigned int*)(k16 + (size_t)node * HID + lane * 2);
    const float knx = bf16pair_lo(knp), kny = bf16pair_hi(knp);
    float accx = 0.f, accy = 0.f, d = 0.f;

    int e = 0;
    for (; e + 4 <= deg; e += 4) {
        int kj[4];
        #pragma unroll
        for (int i = 0; i < 4; ++i) kj[i] = edge_kj[base + e + i];
        unsigned int qp[4], vp[4];
        #pragma unroll
        for (int i = 0; i < 4; ++i) {
            qp[i] = *(const unsigned int*)(q16 + (size_t)kj[i] * HID + lane * 2);
            vp[i] = *(const unsigned int*)(v16 + (size_t)kj[i] * HID + lane * 2);
        }
        float p[4];
        #pragma unroll
        for (int i = 0; i < 4; ++i)
            p[i] = bf16pair_lo(qp[i]) * knx + bf16pair_hi(qp[i]) * kny;
        #pragma unroll
        for (int i = 0; i < 4; ++i) {
            p[i] += __shfl_xor(p[i], 1);
            p[i] += __shfl_xor(p[i], 2);
            p[i] += __shfl_xor(p[i], 4);
        }
        #pragma unroll
        for (int i = 0; i < 4; ++i) {
            float s = (p[i] >= 0.f) ? p[i] : 0.2f * p[i];   // leaky_relu(0.2)
            s = expf(s);
            d += s;
            accx += s * bf16pair_lo(vp[i]);
            accy += s * bf16pair_hi(vp[i]);
        }
    }
    for (; e < deg; ++e) {
        int kj0 = edge_kj[base + e];
        unsigned int qp0 = *(const unsigned int*)(q16 + (size_t)kj0 * HID + lane * 2);
        unsigned int vp0 = *(const unsigned int*)(v16 + (size_t)kj0 * HID + lane * 2);
        float p0 = bf16pair_lo(qp0) * knx + bf16pair_hi(qp0) * kny;
        p0 += __shfl_xor(p0, 1); p0 += __shfl_xor(p0, 2); p0 += __shfl_xor(p0, 4);
        float s0 = (p0 >= 0.f) ? p0 : 0.2f * p0;
        s0 = expf(s0);
        d += s0;
        accx += s0 * bf16pair_lo(vp0);
        accy += s0 * bf16pair_hi(vp0);
    }

    const float inv = (deg > 0) ? 1.f / d : 0.f;     // deg==0 -> zeros, not NaN
    unsigned int outp = (unsigned int)f32_to_bf16(accx * inv)
                      | ((unsigned int)f32_to_bf16(accy * inv) << 16);
    *(unsigned int*)(agg16 + (size_t)node * HID + lane * 2) = outp;
}

// ---------------------------------------------------------------------------
// Residual MLP via bf16 MFMA, operand-swapped in BOTH phases so each lane
// holds 4 consecutive channels of one node row:
//   phase 1 -> ushort4 LDS writes;  phase 2 -> float4 global stores with
//   coalesced ushort4 residual loads.
// ---------------------------------------------------------------------------
#define H1_STRIDE 152
__global__ __launch_bounds__(256) void mlp_mfma_kernel(
    const ushort* __restrict__ agg16, const ushort* __restrict__ v16,
    const ushort* __restrict__ W1_16, const float* __restrict__ b1,
    const ushort* __restrict__ W2_16, const float* __restrict__ b2,
    float* __restrict__ out)
{
    __shared__ ushort h1s[4][16][H1_STRIDE];
    const int wave = threadIdx.x >> 6;
    const int lane = threadIdx.x & 63;
    const int row0 = blockIdx.x * 64 + wave * 16;
    const bool valid = (row0 < N_NODES);
    const int rbase = valid ? row0 : 0;
    const int lrow = lane & 15;
    const int lk   = (lane >> 4) * 8;
    const int crow = (lane >> 4) * 4;

    // phase 1: h1 = relu(agg @ W1.T + b1)  [lane: node=lrow, ch=t*16+crow+r]
    floatx4 acc[8];
    #pragma unroll
    for (int t = 0; t < 8; ++t) acc[t] = (floatx4)(0.f);
    {
        const ushort* arow = agg16 + (size_t)(rbase + lrow) * HID + lk;
        #pragma unroll
        for (int ks = 0; ks < 4; ++ks) {
            short8 a = *(const short8*)(arow + ks * 32);
            const ushort* wbase = W1_16 + (size_t)lrow * HID + ks * 32 + lk;
            #pragma unroll
            for (int t = 0; t < 8; ++t) {
                short8 b = *(const short8*)(wbase + (size_t)t * 16 * HID);
                acc[t] = __builtin_amdgcn_mfma_f32_16x16x32_bf16(b, a, acc[t], 0, 0, 0);
            }
        }
    }
    #pragma unroll
    for (int t = 0; t < 8; ++t) {
        float4 bias = *(const float4*)(b1 + t * 16 + crow);
        ushort4 o;
        o.x = f32_to_bf16(fmaxf(acc[t][0] + bias.x, 0.f));
        o.y = f32_to_bf16(fmaxf(acc[t][1] + bias.y, 0.f));
        o.z = f32_to_bf16(fmaxf(acc[t][2] + bias.z, 0.f));
        o.w = f32_to_bf16(fmaxf(acc[t][3] + bias.w, 0.f));
        *(ushort4*)&h1s[wave][lrow][t * 16 + crow] = o;
    }
    __syncthreads();   // all 256 threads reach this (no early returns)

    // phase 2: h2 = relu(h1 @ W2.T + b2); out = v + h2
    #pragma unroll
    for (int t = 0; t < 8; ++t) acc[t] = (floatx4)(0.f);
    #pragma unroll
    for (int ks = 0; ks < 4; ++ks) {
        short8 a = *(const short8*)&h1s[wave][lrow][ks * 32 + lk];
        const ushort* wbase = W2_16 + (size_t)lrow * HID + ks * 32 + lk;
        #pragma unroll
        for (int t = 0; t < 8; ++t) {
            short8 b = *(const short8*)(wbase + (size_t)t * 16 * HID);
            acc[t] = __builtin_amdgcn_mfma_f32_16x16x32_bf16(b, a, acc[t], 0, 0, 0);
        }
    }
    if (valid) {
        const size_t rowoff = (size_t)(row0 + lrow) * HID;
        #pragma unroll
        for (int t = 0; t < 8; ++t) {
            float4 bias = *(const float4*)(b2 + t * 16 + crow);
            ushort4 vv = *(const ushort4*)(v16 + rowoff + t * 16 + crow);
            float4 o;
            o.x = bf16_bits_to_f32(vv.x) + fmaxf(acc[t][0] + bias.x, 0.f);
            o.y = bf16_bits_to_f32(vv.y) + fmaxf(acc[t][1] + bias.y, 0.f);
            o.z = bf16_bits_to_f32(vv.z) + fmaxf(acc[t][2] + bias.z, 0.f);
            o.w = bf16_bits_to_f32(vv.w) + fmaxf(acc[t][3] + bias.w, 0.f);
            *(float4*)(out + rowoff + t * 16 + crow) = o;
        }
    }
}

extern "C" void kernel_launch(void* const* d_in, const int* in_sizes, int n_in,
                              void* d_out, int out_size, void* d_ws, size_t ws_size,
                              hipStream_t stream) {
    const float* feats  = (const float*)d_in[0];
    const int*   idx_kj = (const int*)d_in[1];
    const int*   idx_ji = (const int*)d_in[2];
    const float* Wv     = (const float*)d_in[3];
    const float* Wq     = (const float*)d_in[4];
    const float* Wk     = (const float*)d_in[5];
    const float* W1     = (const float*)d_in[6];
    const float* b1     = (const float*)d_in[7];
    const float* W2     = (const float*)d_in[8];
    const float* b2     = (const float*)d_in[9];
    float* out = (float*)d_out;

    // workspace layout (bf16 arrays first, all 16B-aligned sizes)
    ushort* q16     = (ushort*)d_ws;
    ushort* k16     = q16     + (size_t)N_NODES * HID;
    ushort* v16     = k16     + (size_t)N_NODES * HID;
    ushort* agg16   = v16     + (size_t)N_NODES * HID;
    ushort* Wq16    = agg16   + (size_t)N_NODES * HID;
    ushort* Wk16    = Wq16 + HID * HID;
    ushort* Wv16    = Wk16 + HID * HID;
    ushort* W116    = Wv16 + HID * HID;
    ushort* W216    = W116 + HID * HID;
    int* count      = (int*)(W216 + HID * HID);
    int* offsets    = count + N_NODES;
    int* cursor     = offsets + N_NODES;
    int* blocksum   = cursor + N_NODES;
    int* edge_kj    = blocksum + ((SCAN_NB + 3) & ~3);

    hipMemsetAsync(count, 0, N_NODES * sizeof(int), stream);

    cvt_w_kernel<<<(5 * HID * HID + 255) / 256, 256, 0, stream>>>(
        Wq, Wk, Wv, W1, W2, Wq16, Wk16, Wv16, W116, W216);

    qkv_mfma_kernel<<<(N_NODES + 63) / 64, 256, 0, stream>>>(
        feats, Wq16, Wk16, Wv16, q16, k16, v16);

    hist_kernel<<<(M_EDGES + 255) / 256, 256, 0, stream>>>(idx_ji, count);
    scan_blocksum_kernel<<<SCAN_NB, 256, 0, stream>>>(count, blocksum);
    scan_top_kernel<<<1, 128, 0, stream>>>(blocksum);
    scan_write_kernel<<<SCAN_NB, 256, 0, stream>>>(count, blocksum, offsets, cursor);
    fill_kernel<<<(M_EDGES + 255) / 256, 256, 0, stream>>>(idx_ji, idx_kj, cursor, edge_kj);

    aggregate_kernel<<<(N_NODES * 64 + 255) / 256, 256, 0, stream>>>(
        edge_kj, offsets, count, q16, k16, v16, agg16);

    mlp_mfma_kernel<<<(N_NODES + 63) / 64, 256, 0, stream>>>(
        agg16, v16, W116, b1, W216, b2, out);
}

// Round 6
// 329.643 us; speedup vs baseline: 6.5552x; 1.2496x over previous
//
#include <hip/hip_runtime.h>
#include <hip/hip_bf16.h>
#include <math.h>

#define N_NODES 100000
#define M_EDGES 800000
#define HID 128
#define HEADS 8
#define DH 16
#define SCAN_NB ((N_NODES + 1023) / 1024)   // 98 blocks of 1024 counts

typedef __attribute__((ext_vector_type(8))) short short8;   // 8 x bf16 (4 VGPRs)
typedef __attribute__((ext_vector_type(4))) float floatx4;  // MFMA accumulator

__device__ __forceinline__ ushort f32_to_bf16(float x) {
    __hip_bfloat16 h = __float2bfloat16(x);   // RNE
    union { __hip_bfloat16 h; ushort u; } c; c.h = h;
    return c.u;
}
__device__ __forceinline__ float bf16_bits_to_f32(ushort u) {
    union { unsigned int i; float f; } c; c.i = ((unsigned int)u) << 16;
    return c.f;
}
__device__ __forceinline__ float bf16pair_lo(unsigned int p) {
    union { unsigned int i; float f; } c; c.i = p << 16; return c.f;
}
__device__ __forceinline__ float bf16pair_hi(unsigned int p) {
    union { unsigned int i; float f; } c; c.i = p & 0xffff0000u; return c.f;
}

// ---------------------------------------------------------------------------
// Stage a 128x128 bf16 weight matrix into LDS in MFMA B-fragment order:
// fragment f = ks*8+t occupies lds[f*512 .. f*512+511] (ushorts), laid out as
// 64 lanes x 8 ushorts.  Source chunk for (f,lane): row = t*16+(lane&15),
// col = ks*32+(lane>>4)*8.  Compute-side read is then ds_read_b128 at
// (f*64+lane)*16 bytes -> contiguous, conflict-free.
// ---------------------------------------------------------------------------
__device__ __forceinline__ void stage_w_frag(const ushort* __restrict__ W,
                                             ushort* __restrict__ lds, int tid)
{
    #pragma unroll
    for (int i = 0; i < 8; ++i) {
        int idx  = i * 256 + tid;       // 0..2047 chunks of 8 ushorts
        int f    = idx >> 6;
        int lane = idx & 63;
        int t    = f & 7, ks = f >> 3;
        int row  = t * 16 + (lane & 15);
        int col  = ks * 32 + (lane >> 4) * 8;
        uint4 d = *(const uint4*)(W + row * HID + col);
        *(uint4*)(lds + idx * 8) = d;
    }
}

// ---------------------------------------------------------------------------
// Convert the five 128x128 weight matrices -> bf16 in one dispatch.
// ---------------------------------------------------------------------------
__global__ __launch_bounds__(256) void cvt_w_kernel(
    const float* __restrict__ Wq, const float* __restrict__ Wk, const float* __restrict__ Wv,
    const float* __restrict__ W1, const float* __restrict__ W2,
    ushort* __restrict__ dq, ushort* __restrict__ dk, ushort* __restrict__ dv,
    ushort* __restrict__ d1, ushort* __restrict__ d2)
{
    int i = blockIdx.x * 256 + threadIdx.x;        // 0 .. 5*16384-1
    int w = i >> 14;
    int j = i & 16383;
    const float* s[5] = {Wq, Wk, Wv, W1, W2};
    ushort*      d[5] = {dq, dk, dv, d1, d2};
    d[w][j] = f32_to_bf16(s[w][j]);
}

// ---------------------------------------------------------------------------
// Q/K/V projection via bf16 MFMA, LDS-staged weights.
// Block = 256 threads = 4 waves; block covers 128 rows (wave: 2 tiles of 16).
// Weights staged one at a time into 32KB LDS in fragment order; B fragments
// hoisted to registers per ks-slice and reused across both row tiles.
// Operand-swapped MFMA: lane holds 4 consecutive channels of one node row.
// ---------------------------------------------------------------------------
__global__ __launch_bounds__(256) void qkv_mfma_kernel(
    const float* __restrict__ feats,
    const ushort* __restrict__ Wq16, const ushort* __restrict__ Wk16, const ushort* __restrict__ Wv16,
    ushort* __restrict__ q16, ushort* __restrict__ k16, ushort* __restrict__ v16)
{
    __shared__ ushort wlds[16384];                 // 32 KB, one W at a time
    const int tid  = threadIdx.x;
    const int wave = tid >> 6;
    const int lane = tid & 63;
    const int row0 = blockIdx.x * 128 + wave * 32;
    const int lrow = lane & 15;
    const int lk   = (lane >> 4) * 8;
    const int crow = (lane >> 4) * 4;

    // A fragments for 2 tiles x 4 ks, converted fp32->bf16 in-reg (N%16==0).
    short8 afrag[2][4];
    bool tvalid[2];
    #pragma unroll
    for (int r = 0; r < 2; ++r) {
        int rr = row0 + r * 16;
        tvalid[r] = (rr < N_NODES);
        const float* arow = feats + (size_t)((tvalid[r] ? rr : 0) + lrow) * HID + lk;
        #pragma unroll
        for (int ks = 0; ks < 4; ++ks) {
            float4 f0 = *(const float4*)(arow + ks * 32);
            float4 f1 = *(const float4*)(arow + ks * 32 + 4);
            short8 a;
            a[0] = (short)f32_to_bf16(f0.x); a[1] = (short)f32_to_bf16(f0.y);
            a[2] = (short)f32_to_bf16(f0.z); a[3] = (short)f32_to_bf16(f0.w);
            a[4] = (short)f32_to_bf16(f1.x); a[5] = (short)f32_to_bf16(f1.y);
            a[6] = (short)f32_to_bf16(f1.z); a[7] = (short)f32_to_bf16(f1.w);
            afrag[r][ks] = a;
        }
    }

    const ushort* Ws[3] = {Wq16, Wk16, Wv16};
    ushort*       Os[3] = {q16, k16, v16};

    #pragma unroll
    for (int w = 0; w < 3; ++w) {
        __syncthreads();                           // prior reads of wlds done
        stage_w_frag(Ws[w], wlds, tid);
        __syncthreads();

        floatx4 acc[2][8];
        #pragma unroll
        for (int r = 0; r < 2; ++r)
            #pragma unroll
            for (int t = 0; t < 8; ++t) acc[r][t] = (floatx4)(0.f);

        #pragma unroll
        for (int ks = 0; ks < 4; ++ks) {
            short8 B[8];
            #pragma unroll
            for (int t = 0; t < 8; ++t)
                B[t] = *(const short8*)&wlds[(ks * 8 + t) * 512 + lane * 8];
            #pragma unroll
            for (int t = 0; t < 8; ++t) {
                acc[0][t] = __builtin_amdgcn_mfma_f32_16x16x32_bf16(B[t], afrag[0][ks], acc[0][t], 0, 0, 0);
                acc[1][t] = __builtin_amdgcn_mfma_f32_16x16x32_bf16(B[t], afrag[1][ks], acc[1][t], 0, 0, 0);
            }
        }

        #pragma unroll
        for (int r = 0; r < 2; ++r) {
            if (tvalid[r]) {
                ushort* O = Os[w] + (size_t)(row0 + r * 16 + lrow) * HID;
                #pragma unroll
                for (int t = 0; t < 8; ++t) {
                    ushort4 o;
                    o.x = f32_to_bf16(acc[r][t][0]); o.y = f32_to_bf16(acc[r][t][1]);
                    o.z = f32_to_bf16(acc[r][t][2]); o.w = f32_to_bf16(acc[r][t][3]);
                    *(ushort4*)(O + t * 16 + crow) = o;
                }
            }
        }
    }
}

// ---------------------------------------------------------------------------
// CSR build: histogram -> 3-stage device-wide scan -> fill (stores kj direct).
// ---------------------------------------------------------------------------
__global__ __launch_bounds__(256) void hist_kernel(
    const int* __restrict__ idx_ji, int* __restrict__ count)
{
    int m = blockIdx.x * 256 + threadIdx.x;
    if (m < M_EDGES) atomicAdd(&count[idx_ji[m]], 1);
}

__global__ __launch_bounds__(256) void scan_blocksum_kernel(
    const int* __restrict__ count, int* __restrict__ blocksum)
{
    __shared__ int s[256];
    const int tid = threadIdx.x;
    const int base = blockIdx.x * 1024 + tid * 4;
    int sum = 0;
    if (base + 3 < N_NODES) {
        int4 c = *(const int4*)(count + base);
        sum = c.x + c.y + c.z + c.w;
    } else {
        #pragma unroll
        for (int j = 0; j < 4; ++j) if (base + j < N_NODES) sum += count[base + j];
    }
    s[tid] = sum;
    __syncthreads();
    for (int off = 128; off > 0; off >>= 1) {
        if (tid < off) s[tid] += s[tid + off];
        __syncthreads();
    }
    if (tid == 0) blocksum[blockIdx.x] = s[0];
}

__global__ __launch_bounds__(128) void scan_top_kernel(int* __restrict__ blocksum)
{
    __shared__ int s[128];
    const int t = threadIdx.x;
    int v = (t < SCAN_NB) ? blocksum[t] : 0;
    s[t] = v;
    __syncthreads();
    for (int off = 1; off < 128; off <<= 1) {
        int x = (t >= off) ? s[t - off] : 0;
        __syncthreads();
        s[t] += x;
        __syncthreads();
    }
    if (t < SCAN_NB) blocksum[t] = s[t] - v;   // exclusive
}

__global__ __launch_bounds__(256) void scan_write_kernel(
    const int* __restrict__ count, const int* __restrict__ blocksum,
    int* __restrict__ offsets, int* __restrict__ cursor)
{
    __shared__ int s[256];
    const int tid = threadIdx.x;
    const int base = blockIdx.x * 1024 + tid * 4;
    int c0 = 0, c1 = 0, c2 = 0, c3 = 0;
    if (base + 3 < N_NODES) {
        int4 c = *(const int4*)(count + base);
        c0 = c.x; c1 = c.y; c2 = c.z; c3 = c.w;
    } else {
        if (base     < N_NODES) c0 = count[base];
        if (base + 1 < N_NODES) c1 = count[base + 1];
        if (base + 2 < N_NODES) c2 = count[base + 2];
        if (base + 3 < N_NODES) c3 = count[base + 3];
    }
    const int tsum = c0 + c1 + c2 + c3;
    s[tid] = tsum;
    __syncthreads();
    for (int off = 1; off < 256; off <<= 1) {
        int x = (tid >= off) ? s[tid - off] : 0;
        __syncthreads();
        s[tid] += x;
        __syncthreads();
    }
    int o0 = s[tid] - tsum + blocksum[blockIdx.x];
    int o1 = o0 + c0, o2 = o1 + c1, o3 = o2 + c2;
    if (base + 3 < N_NODES) {
        *(int4*)(offsets + base) = make_int4(o0, o1, o2, o3);
        *(int4*)(cursor  + base) = make_int4(o0, o1, o2, o3);
    } else {
        if (base     < N_NODES) { offsets[base]     = o0; cursor[base]     = o0; }
        if (base + 1 < N_NODES) { offsets[base + 1] = o1; cursor[base + 1] = o1; }
        if (base + 2 < N_NODES) { offsets[base + 2] = o2; cursor[base + 2] = o2; }
        if (base + 3 < N_NODES) { offsets[base + 3] = o3; cursor[base + 3] = o3; }
    }
}

__global__ __launch_bounds__(256) void fill_kernel(
    const int* __restrict__ idx_ji, const int* __restrict__ idx_kj,
    int* __restrict__ cursor, int* __restrict__ edge_kj)
{
    int m = blockIdx.x * 256 + threadIdx.x;
    if (m < M_EDGES) {
        int pos = atomicAdd(&cursor[idx_ji[m]], 1);
        edge_kj[pos] = idx_kj[m];
    }
}

// ---------------------------------------------------------------------------
// Fused attention + normalized aggregation, gather-style, bf16 in/out.
// One wave per destination node; lane owns channels 2*lane, 2*lane+1
// (head = lane/8).  4-edge unroll: 8 independent row-gathers in flight.
// ---------------------------------------------------------------------------
__global__ __launch_bounds__(256) void aggregate_kernel(
    const int* __restrict__ edge_kj, const int* __restrict__ offsets,
    const int* __restrict__ count, const ushort* __restrict__ q16,
    const ushort* __restrict__ k16, const ushort* __restrict__ v16,
    ushort* __restrict__ agg16)
{
    int gid  = blockIdx.x * 256 + threadIdx.x;
    int node = gid >> 6;
    int lane = threadIdx.x & 63;
    if (node >= N_NODES) return;

    const int deg  = count[node];
    const int base = offsets[node];

    unsigned int knp = *(const unsigned int*)(k16 + (size_t)node * HID + lane * 2);
    const float knx = bf16pair_lo(knp), kny = bf16pair_hi(knp);
    float accx = 0.f, accy = 0.f, d = 0.f;

    int e = 0;
    for (; e + 4 <= deg; e += 4) {
        int kj[4];
        #pragma unroll
        for (int i = 0; i < 4; ++i) kj[i] = edge_kj[base + e + i];
        unsigned int qp[4], vp[4];
        #pragma unroll
        for (int i = 0; i < 4; ++i) {
            qp[i] = *(const unsigned int*)(q16 + (size_t)kj[i] * HID + lane * 2);
            vp[i] = *(const unsigned int*)(v16 + (size_t)kj[i] * HID + lane * 2);
        }
        float p[4];
        #pragma unroll
        for (int i = 0; i < 4; ++i)
            p[i] = bf16pair_lo(qp[i]) * knx + bf16pair_hi(qp[i]) * kny;
        #pragma unroll
        for (int i = 0; i < 4; ++i) {
            p[i] += __shfl_xor(p[i], 1);
            p[i] += __shfl_xor(p[i], 2);
            p[i] += __shfl_xor(p[i], 4);
        }
        #pragma unroll
        for (int i = 0; i < 4; ++i) {
            float s = (p[i] >= 0.f) ? p[i] : 0.2f * p[i];   // leaky_relu(0.2)
            s = expf(s);
            d += s;
            accx += s * bf16pair_lo(vp[i]);
            accy += s * bf16pair_hi(vp[i]);
        }
    }
    for (; e < deg; ++e) {
        int kj0 = edge_kj[base + e];
        unsigned int qp0 = *(const unsigned int*)(q16 + (size_t)kj0 * HID + lane * 2);
        unsigned int vp0 = *(const unsigned int*)(v16 + (size_t)kj0 * HID + lane * 2);
        float p0 = bf16pair_lo(qp0) * knx + bf16pair_hi(qp0) * kny;
        p0 += __shfl_xor(p0, 1); p0 += __shfl_xor(p0, 2); p0 += __shfl_xor(p0, 4);
        float s0 = (p0 >= 0.f) ? p0 : 0.2f * p0;
        s0 = expf(s0);
        d += s0;
        accx += s0 * bf16pair_lo(vp0);
        accy += s0 * bf16pair_hi(vp0);
    }

    const float inv = (deg > 0) ? 1.f / d : 0.f;     // deg==0 -> zeros, not NaN
    unsigned int outp = (unsigned int)f32_to_bf16(accx * inv)
                      | ((unsigned int)f32_to_bf16(accy * inv) << 16);
    *(unsigned int*)(agg16 + (size_t)node * HID + lane * 2) = outp;
}

// ---------------------------------------------------------------------------
// Residual MLP via bf16 MFMA, LDS-staged weights (W1 then W2 in one 32KB
// buffer), 128 rows/block.  h1 round-trips through LDS directly in MFMA
// A-fragment order (chunk (ks,quad,lrow) of tile -> 8 ushorts), so phase-2
// A-reads are contiguous ds_read_b128.  Operand-swapped in both phases.
// ---------------------------------------------------------------------------
__global__ __launch_bounds__(256) void mlp_mfma_kernel(
    const ushort* __restrict__ agg16, const ushort* __restrict__ v16,
    const ushort* __restrict__ W1_16, const float* __restrict__ b1,
    const ushort* __restrict__ W2_16, const float* __restrict__ b2,
    float* __restrict__ out)
{
    __shared__ ushort wlds[16384];    // 32 KB: W1, then W2
    __shared__ ushort h1s[16384];     // 32 KB: 8 tiles x 2048 ushorts (frag order)
    const int tid  = threadIdx.x;
    const int wave = tid >> 6;
    const int lane = tid & 63;
    const int row0 = blockIdx.x * 128 + wave * 32;
    const int lrow = lane & 15;
    const int lk   = (lane >> 4) * 8;
    const int crow = (lane >> 4) * 4;

    // phase 0: load agg A-fragments (2 tiles x 4 ks)
    short8 afrag[2][4];
    bool tvalid[2];
    #pragma unroll
    for (int r = 0; r < 2; ++r) {
        int rr = row0 + r * 16;
        tvalid[r] = (rr < N_NODES);
        const ushort* arow = agg16 + (size_t)((tvalid[r] ? rr : 0) + lrow) * HID + lk;
        #pragma unroll
        for (int ks = 0; ks < 4; ++ks)
            afrag[r][ks] = *(const short8*)(arow + ks * 32);
    }

    stage_w_frag(W1_16, wlds, tid);
    __syncthreads();

    // phase 1: h1 = relu(agg @ W1.T + b1) -> h1s in A-fragment order
    {
        floatx4 acc[2][8];
        #pragma unroll
        for (int r = 0; r < 2; ++r)
            #pragma unroll
            for (int t = 0; t < 8; ++t) acc[r][t] = (floatx4)(0.f);
        #pragma unroll
        for (int ks = 0; ks < 4; ++ks) {
            short8 B[8];
            #pragma unroll
            for (int t = 0; t < 8; ++t)
                B[t] = *(const short8*)&wlds[(ks * 8 + t) * 512 + lane * 8];
            #pragma unroll
            for (int t = 0; t < 8; ++t) {
                acc[0][t] = __builtin_amdgcn_mfma_f32_16x16x32_bf16(B[t], afrag[0][ks], acc[0][t], 0, 0, 0);
                acc[1][t] = __builtin_amdgcn_mfma_f32_16x16x32_bf16(B[t], afrag[1][ks], acc[1][t], 0, 0, 0);
            }
        }
        // write h1 in fragment order: ch = t*16+crow+{0..3} of node lrow
        //   -> chunk (ks = t>>1, quad = (t&1)*2 + (crow>>3), lrow), half j0 = crow&4
        #pragma unroll
        for (int r = 0; r < 2; ++r) {
            ushort* tile = &h1s[(wave * 2 + r) * 2048];
            #pragma unroll
            for (int t = 0; t < 8; ++t) {
                float4 bias = *(const float4*)(b1 + t * 16 + crow);
                ushort4 o;
                o.x = f32_to_bf16(fmaxf(acc[r][t][0] + bias.x, 0.f));
                o.y = f32_to_bf16(fmaxf(acc[r][t][1] + bias.y, 0.f));
                o.z = f32_to_bf16(fmaxf(acc[r][t][2] + bias.z, 0.f));
                o.w = f32_to_bf16(fmaxf(acc[r][t][3] + bias.w, 0.f));
                int ks   = t >> 1;
                int quad = (t & 1) * 2 + (crow >> 3);
                int j0   = crow & 4;
                *(ushort4*)(tile + (ks * 64 + quad * 16 + lrow) * 8 + j0) = o;
            }
        }
    }
    __syncthreads();                    // h1 written, wlds reads done
    stage_w_frag(W2_16, wlds, tid);     // overwrite with W2
    __syncthreads();

    // phase 2: h2 = relu(h1 @ W2.T + b2); out = v + h2
    {
        short8 hfrag[2][4];
        #pragma unroll
        for (int r = 0; r < 2; ++r) {
            const ushort* tile = &h1s[(wave * 2 + r) * 2048];
            #pragma unroll
            for (int ks = 0; ks < 4; ++ks)
                hfrag[r][ks] = *(const short8*)(tile + (ks * 64 + lane) * 8);
        }
        floatx4 acc[2][8];
        #pragma unroll
        for (int r = 0; r < 2; ++r)
            #pragma unroll
            for (int t = 0; t < 8; ++t) acc[r][t] = (floatx4)(0.f);
        #pragma unroll
        for (int ks = 0; ks < 4; ++ks) {
            short8 B[8];
            #pragma unroll
            for (int t = 0; t < 8; ++t)
                B[t] = *(const short8*)&wlds[(ks * 8 + t) * 512 + lane * 8];
            #pragma unroll
            for (int t = 0; t < 8; ++t) {
                acc[0][t] = __builtin_amdgcn_mfma_f32_16x16x32_bf16(B[t], hfrag[0][ks], acc[0][t], 0, 0, 0);
                acc[1][t] = __builtin_amdgcn_mfma_f32_16x16x32_bf16(B[t], hfrag[1][ks], acc[1][t], 0, 0, 0);
            }
        }
        #pragma unroll
        for (int r = 0; r < 2; ++r) {
            if (tvalid[r]) {
                const size_t rowoff = (size_t)(row0 + r * 16 + lrow) * HID;
                #pragma unroll
                for (int t = 0; t < 8; ++t) {
                    float4 bias = *(const float4*)(b2 + t * 16 + crow);
                    ushort4 vv = *(const ushort4*)(v16 + rowoff + t * 16 + crow);
                    float4 o;
                    o.x = bf16_bits_to_f32(vv.x) + fmaxf(acc[r][t][0] + bias.x, 0.f);
                    o.y = bf16_bits_to_f32(vv.y) + fmaxf(acc[r][t][1] + bias.y, 0.f);
                    o.z = bf16_bits_to_f32(vv.z) + fmaxf(acc[r][t][2] + bias.z, 0.f);
                    o.w = bf16_bits_to_f32(vv.w) + fmaxf(acc[r][t][3] + bias.w, 0.f);
                    *(float4*)(out + rowoff + t * 16 + crow) = o;
                }
            }
        }
    }
}

extern "C" void kernel_launch(void* const* d_in, const int* in_sizes, int n_in,
                              void* d_out, int out_size, void* d_ws, size_t ws_size,
                              hipStream_t stream) {
    const float* feats  = (const float*)d_in[0];
    const int*   idx_kj = (const int*)d_in[1];
    const int*   idx_ji = (const int*)d_in[2];
    const float* Wv     = (const float*)d_in[3];
    const float* Wq     = (const float*)d_in[4];
    const float* Wk     = (const float*)d_in[5];
    const float* W1     = (const float*)d_in[6];
    const float* b1     = (const float*)d_in[7];
    const float* W2     = (const float*)d_in[8];
    const float* b2     = (const float*)d_in[9];
    float* out = (float*)d_out;

    // workspace layout (bf16 arrays first, all 16B-aligned sizes)
    ushort* q16     = (ushort*)d_ws;
    ushort* k16     = q16     + (size_t)N_NODES * HID;
    ushort* v16     = k16     + (size_t)N_NODES * HID;
    ushort* agg16   = v16     + (size_t)N_NODES * HID;
    ushort* Wq16    = agg16   + (size_t)N_NODES * HID;
    ushort* Wk16    = Wq16 + HID * HID;
    ushort* Wv16    = Wk16 + HID * HID;
    ushort* W116    = Wv16 + HID * HID;
    ushort* W216    = W116 + HID * HID;
    int* count      = (int*)(W216 + HID * HID);
    int* offsets    = count + N_NODES;
    int* cursor     = offsets + N_NODES;
    int* blocksum   = cursor + N_NODES;
    int* edge_kj    = blocksum + ((SCAN_NB + 3) & ~3);

    hipMemsetAsync(count, 0, N_NODES * sizeof(int), stream);

    cvt_w_kernel<<<(5 * HID * HID + 255) / 256, 256, 0, stream>>>(
        Wq, Wk, Wv, W1, W2, Wq16, Wk16, Wv16, W116, W216);

    qkv_mfma_kernel<<<(N_NODES + 127) / 128, 256, 0, stream>>>(
        feats, Wq16, Wk16, Wv16, q16, k16, v16);

    hist_kernel<<<(M_EDGES + 255) / 256, 256, 0, stream>>>(idx_ji, count);
    scan_blocksum_kernel<<<SCAN_NB, 256, 0, stream>>>(count, blocksum);
    scan_top_kernel<<<1, 128, 0, stream>>>(blocksum);
    scan_write_kernel<<<SCAN_NB, 256, 0, stream>>>(count, blocksum, offsets, cursor);
    fill_kernel<<<(M_EDGES + 255) / 256, 256, 0, stream>>>(idx_ji, idx_kj, cursor, edge_kj);

    aggregate_kernel<<<(N_NODES * 64 + 255) / 256, 256, 0, stream>>>(
        edge_kj, offsets, count, q16, k16, v16, agg16);

    mlp_mfma_kernel<<<(N_NODES + 127) / 128, 256, 0, stream>>>(
        agg16, v16, W116, b1, W216, b2, out);
}

// Round 7
// 328.506 us; speedup vs baseline: 6.5779x; 1.0035x over previous
//
#include <hip/hip_runtime.h>
#include <hip/hip_bf16.h>
#include <math.h>

#define N_NODES 100000
#define M_EDGES 800000
#define HID 128
#define HEADS 8
#define DH 16
#define SCAN_NB ((N_NODES + 1023) / 1024)   // 98 blocks of 1024 counts

typedef __attribute__((ext_vector_type(8))) short short8;   // 8 x bf16 (4 VGPRs)
typedef __attribute__((ext_vector_type(4))) float floatx4;  // MFMA accumulator

__device__ __forceinline__ ushort f32_to_bf16(float x) {
    __hip_bfloat16 h = __float2bfloat16(x);   // RNE
    union { __hip_bfloat16 h; ushort u; } c; c.h = h;
    return c.u;
}
__device__ __forceinline__ float bf16_bits_to_f32(ushort u) {
    union { unsigned int i; float f; } c; c.i = ((unsigned int)u) << 16;
    return c.f;
}
__device__ __forceinline__ float bf16pair_lo(unsigned int p) {
    union { unsigned int i; float f; } c; c.i = p << 16; return c.f;
}
__device__ __forceinline__ float bf16pair_hi(unsigned int p) {
    union { unsigned int i; float f; } c; c.i = p & 0xffff0000u; return c.f;
}

// ---------------------------------------------------------------------------
// Stage a 128x128 bf16 weight matrix into LDS in MFMA B-fragment order.
// ---------------------------------------------------------------------------
__device__ __forceinline__ void stage_w_frag(const ushort* __restrict__ W,
                                             ushort* __restrict__ lds, int tid)
{
    #pragma unroll
    for (int i = 0; i < 8; ++i) {
        int idx  = i * 256 + tid;       // 0..2047 chunks of 8 ushorts
        int f    = idx >> 6;
        int lane = idx & 63;
        int t    = f & 7, ks = f >> 3;
        int row  = t * 16 + (lane & 15);
        int col  = ks * 32 + (lane >> 4) * 8;
        uint4 d = *(const uint4*)(W + row * HID + col);
        *(uint4*)(lds + idx * 8) = d;
    }
}

// ---------------------------------------------------------------------------
// Convert the five 128x128 weight matrices -> bf16 in one dispatch.
// ---------------------------------------------------------------------------
__global__ __launch_bounds__(256) void cvt_w_kernel(
    const float* __restrict__ Wq, const float* __restrict__ Wk, const float* __restrict__ Wv,
    const float* __restrict__ W1, const float* __restrict__ W2,
    ushort* __restrict__ dq, ushort* __restrict__ dk, ushort* __restrict__ dv,
    ushort* __restrict__ d1, ushort* __restrict__ d2)
{
    int i = blockIdx.x * 256 + threadIdx.x;        // 0 .. 5*16384-1
    int w = i >> 14;
    int j = i & 16383;
    const float* s[5] = {Wq, Wk, Wv, W1, W2};
    ushort*      d[5] = {dq, dk, dv, d1, d2};
    d[w][j] = f32_to_bf16(s[w][j]);
}

// ---------------------------------------------------------------------------
// Q/K/V projection via bf16 MFMA, LDS-staged weights, 128 rows/block.
// q and v go into the INTERLEAVED qv buffer (node stride 256: q then v);
// k goes into its own [node][128] array.
// ---------------------------------------------------------------------------
__global__ __launch_bounds__(256) void qkv_mfma_kernel(
    const float* __restrict__ feats,
    const ushort* __restrict__ Wq16, const ushort* __restrict__ Wk16, const ushort* __restrict__ Wv16,
    ushort* __restrict__ qv16, ushort* __restrict__ k16)
{
    __shared__ ushort wlds[16384];                 // 32 KB, one W at a time
    const int tid  = threadIdx.x;
    const int wave = tid >> 6;
    const int lane = tid & 63;
    const int row0 = blockIdx.x * 128 + wave * 32;
    const int lrow = lane & 15;
    const int lk   = (lane >> 4) * 8;
    const int crow = (lane >> 4) * 4;

    // A fragments for 2 tiles x 4 ks, converted fp32->bf16 in-reg (N%16==0).
    short8 afrag[2][4];
    bool tvalid[2];
    #pragma unroll
    for (int r = 0; r < 2; ++r) {
        int rr = row0 + r * 16;
        tvalid[r] = (rr < N_NODES);
        const float* arow = feats + (size_t)((tvalid[r] ? rr : 0) + lrow) * HID + lk;
        #pragma unroll
        for (int ks = 0; ks < 4; ++ks) {
            float4 f0 = *(const float4*)(arow + ks * 32);
            float4 f1 = *(const float4*)(arow + ks * 32 + 4);
            short8 a;
            a[0] = (short)f32_to_bf16(f0.x); a[1] = (short)f32_to_bf16(f0.y);
            a[2] = (short)f32_to_bf16(f0.z); a[3] = (short)f32_to_bf16(f0.w);
            a[4] = (short)f32_to_bf16(f1.x); a[5] = (short)f32_to_bf16(f1.y);
            a[6] = (short)f32_to_bf16(f1.z); a[7] = (short)f32_to_bf16(f1.w);
            afrag[r][ks] = a;
        }
    }

    const ushort* Ws[3] = {Wq16, Wk16, Wv16};
    // output bases and per-node strides: q -> qv+0 (256), k -> k16 (128), v -> qv+128 (256)
    ushort* Ob[3]; int Ostride[3];
    Ob[0] = qv16;       Ostride[0] = 256;
    Ob[1] = k16;        Ostride[1] = 128;
    Ob[2] = qv16 + 128; Ostride[2] = 256;

    #pragma unroll
    for (int w = 0; w < 3; ++w) {
        __syncthreads();                           // prior reads of wlds done
        stage_w_frag(Ws[w], wlds, tid);
        __syncthreads();

        floatx4 acc[2][8];
        #pragma unroll
        for (int r = 0; r < 2; ++r)
            #pragma unroll
            for (int t = 0; t < 8; ++t) acc[r][t] = (floatx4)(0.f);

        #pragma unroll
        for (int ks = 0; ks < 4; ++ks) {
            short8 B[8];
            #pragma unroll
            for (int t = 0; t < 8; ++t)
                B[t] = *(const short8*)&wlds[(ks * 8 + t) * 512 + lane * 8];
            #pragma unroll
            for (int t = 0; t < 8; ++t) {
                acc[0][t] = __builtin_amdgcn_mfma_f32_16x16x32_bf16(B[t], afrag[0][ks], acc[0][t], 0, 0, 0);
                acc[1][t] = __builtin_amdgcn_mfma_f32_16x16x32_bf16(B[t], afrag[1][ks], acc[1][t], 0, 0, 0);
            }
        }

        #pragma unroll
        for (int r = 0; r < 2; ++r) {
            if (tvalid[r]) {
                ushort* O = Ob[w] + (size_t)(row0 + r * 16 + lrow) * Ostride[w];
                #pragma unroll
                for (int t = 0; t < 8; ++t) {
                    ushort4 o;
                    o.x = f32_to_bf16(acc[r][t][0]); o.y = f32_to_bf16(acc[r][t][1]);
                    o.z = f32_to_bf16(acc[r][t][2]); o.w = f32_to_bf16(acc[r][t][3]);
                    *(ushort4*)(O + t * 16 + crow) = o;
                }
            }
        }
    }
}

// ---------------------------------------------------------------------------
// CSR build: histogram -> 3-stage device-wide scan -> fill (stores kj direct).
// ---------------------------------------------------------------------------
__global__ __launch_bounds__(256) void hist_kernel(
    const int* __restrict__ idx_ji, int* __restrict__ count)
{
    int m = blockIdx.x * 256 + threadIdx.x;
    if (m < M_EDGES) atomicAdd(&count[idx_ji[m]], 1);
}

__global__ __launch_bounds__(256) void scan_blocksum_kernel(
    const int* __restrict__ count, int* __restrict__ blocksum)
{
    __shared__ int s[256];
    const int tid = threadIdx.x;
    const int base = blockIdx.x * 1024 + tid * 4;
    int sum = 0;
    if (base + 3 < N_NODES) {
        int4 c = *(const int4*)(count + base);
        sum = c.x + c.y + c.z + c.w;
    } else {
        #pragma unroll
        for (int j = 0; j < 4; ++j) if (base + j < N_NODES) sum += count[base + j];
    }
    s[tid] = sum;
    __syncthreads();
    for (int off = 128; off > 0; off >>= 1) {
        if (tid < off) s[tid] += s[tid + off];
        __syncthreads();
    }
    if (tid == 0) blocksum[blockIdx.x] = s[0];
}

__global__ __launch_bounds__(128) void scan_top_kernel(int* __restrict__ blocksum)
{
    __shared__ int s[128];
    const int t = threadIdx.x;
    int v = (t < SCAN_NB) ? blocksum[t] : 0;
    s[t] = v;
    __syncthreads();
    for (int off = 1; off < 128; off <<= 1) {
        int x = (t >= off) ? s[t - off] : 0;
        __syncthreads();
        s[t] += x;
        __syncthreads();
    }
    if (t < SCAN_NB) blocksum[t] = s[t] - v;   // exclusive
}

__global__ __launch_bounds__(256) void scan_write_kernel(
    const int* __restrict__ count, const int* __restrict__ blocksum,
    int* __restrict__ offsets, int* __restrict__ cursor)
{
    __shared__ int s[256];
    const int tid = threadIdx.x;
    const int base = blockIdx.x * 1024 + tid * 4;
    int c0 = 0, c1 = 0, c2 = 0, c3 = 0;
    if (base + 3 < N_NODES) {
        int4 c = *(const int4*)(count + base);
        c0 = c.x; c1 = c.y; c2 = c.z; c3 = c.w;
    } else {
        if (base     < N_NODES) c0 = count[base];
        if (base + 1 < N_NODES) c1 = count[base + 1];
        if (base + 2 < N_NODES) c2 = count[base + 2];
        if (base + 3 < N_NODES) c3 = count[base + 3];
    }
    const int tsum = c0 + c1 + c2 + c3;
    s[tid] = tsum;
    __syncthreads();
    for (int off = 1; off < 256; off <<= 1) {
        int x = (tid >= off) ? s[tid - off] : 0;
        __syncthreads();
        s[tid] += x;
        __syncthreads();
    }
    int o0 = s[tid] - tsum + blocksum[blockIdx.x];
    int o1 = o0 + c0, o2 = o1 + c1, o3 = o2 + c2;
    if (base + 3 < N_NODES) {
        *(int4*)(offsets + base) = make_int4(o0, o1, o2, o3);
        *(int4*)(cursor  + base) = make_int4(o0, o1, o2, o3);
    } else {
        if (base     < N_NODES) { offsets[base]     = o0; cursor[base]     = o0; }
        if (base + 1 < N_NODES) { offsets[base + 1] = o1; cursor[base + 1] = o1; }
        if (base + 2 < N_NODES) { offsets[base + 2] = o2; cursor[base + 2] = o2; }
        if (base + 3 < N_NODES) { offsets[base + 3] = o3; cursor[base + 3] = o3; }
    }
}

__global__ __launch_bounds__(256) void fill_kernel(
    const int* __restrict__ idx_ji, const int* __restrict__ idx_kj,
    int* __restrict__ cursor, int* __restrict__ edge_kj)
{
    int m = blockIdx.x * 256 + threadIdx.x;
    if (m < M_EDGES) {
        int pos = atomicAdd(&cursor[idx_ji[m]], 1);
        edge_kj[pos] = idx_kj[m];
    }
}

// ---------------------------------------------------------------------------
// Fused attention + normalized aggregation: 16 LANES PER NODE (4 nodes/wave),
// 8 channels/lane via uint4 (16B) gathers from the interleaved qv buffer.
// Head = 16 ch = 2 lanes -> score reduction is ONE shfl_xor.  Per-subgroup
// edge loops diverge naturally under exec masking.  fp32 accum, no atomics.
// ---------------------------------------------------------------------------
__global__ __launch_bounds__(256) void aggregate_kernel(
    const int* __restrict__ edge_kj, const int* __restrict__ offsets,
    const int* __restrict__ count, const ushort* __restrict__ qv16,
    const ushort* __restrict__ k16, ushort* __restrict__ agg16)
{
    const int gid  = blockIdx.x * 256 + threadIdx.x;
    const int node = gid >> 4;
    const int l16  = threadIdx.x & 15;
    if (node >= N_NODES) return;

    const int deg  = count[node];
    const int base = offsets[node];

    // k fragment: 8 channels of this node's k row
    float kn[8];
    {
        uint4 kp = *(const uint4*)(k16 + (size_t)node * HID + l16 * 8);
        const unsigned int* kw = (const unsigned int*)&kp;
        #pragma unroll
        for (int j = 0; j < 4; ++j) {
            kn[2*j]   = bf16pair_lo(kw[j]);
            kn[2*j+1] = bf16pair_hi(kw[j]);
        }
    }

    float acc[8] = {0.f,0.f,0.f,0.f,0.f,0.f,0.f,0.f};
    float d = 0.f;

    int e = 0;
    for (; e + 2 <= deg; e += 2) {
        const int kj0 = edge_kj[base + e];
        const int kj1 = edge_kj[base + e + 1];
        const ushort* r0 = qv16 + (size_t)kj0 * 256 + l16 * 8;
        const ushort* r1 = qv16 + (size_t)kj1 * 256 + l16 * 8;
        uint4 qp0 = *(const uint4*)r0;
        uint4 vp0 = *(const uint4*)(r0 + 128);
        uint4 qp1 = *(const uint4*)r1;
        uint4 vp1 = *(const uint4*)(r1 + 128);

        const unsigned int* q0 = (const unsigned int*)&qp0;
        const unsigned int* q1 = (const unsigned int*)&qp1;
        float p0 = 0.f, p1 = 0.f;
        #pragma unroll
        for (int j = 0; j < 4; ++j) {
            p0 += bf16pair_lo(q0[j]) * kn[2*j] + bf16pair_hi(q0[j]) * kn[2*j+1];
            p1 += bf16pair_lo(q1[j]) * kn[2*j] + bf16pair_hi(q1[j]) * kn[2*j+1];
        }
        p0 += __shfl_xor(p0, 1);
        p1 += __shfl_xor(p1, 1);
        float lr0 = (p0 >= 0.f) ? p0 : 0.2f * p0;
        float lr1 = (p1 >= 0.f) ? p1 : 0.2f * p1;
        float s0 = __expf(lr0);
        float s1 = __expf(lr1);
        d += s0 + s1;
        const unsigned int* v0 = (const unsigned int*)&vp0;
        const unsigned int* v1 = (const unsigned int*)&vp1;
        #pragma unroll
        for (int j = 0; j < 4; ++j) {
            acc[2*j]   += s0 * bf16pair_lo(v0[j]) + s1 * bf16pair_lo(v1[j]);
            acc[2*j+1] += s0 * bf16pair_hi(v0[j]) + s1 * bf16pair_hi(v1[j]);
        }
    }
    if (e < deg) {
        const int kj0 = edge_kj[base + e];
        const ushort* r0 = qv16 + (size_t)kj0 * 256 + l16 * 8;
        uint4 qp0 = *(const uint4*)r0;
        uint4 vp0 = *(const uint4*)(r0 + 128);
        const unsigned int* q0 = (const unsigned int*)&qp0;
        float p0 = 0.f;
        #pragma unroll
        for (int j = 0; j < 4; ++j)
            p0 += bf16pair_lo(q0[j]) * kn[2*j] + bf16pair_hi(q0[j]) * kn[2*j+1];
        p0 += __shfl_xor(p0, 1);
        float lr0 = (p0 >= 0.f) ? p0 : 0.2f * p0;
        float s0 = __expf(lr0);
        d += s0;
        const unsigned int* v0 = (const unsigned int*)&vp0;
        #pragma unroll
        for (int j = 0; j < 4; ++j) {
            acc[2*j]   += s0 * bf16pair_lo(v0[j]);
            acc[2*j+1] += s0 * bf16pair_hi(v0[j]);
        }
    }

    const float inv = (deg > 0) ? 1.f / d : 0.f;     // deg==0 -> zeros, not NaN
    uint4 o;
    unsigned int* ow = (unsigned int*)&o;
    #pragma unroll
    for (int j = 0; j < 4; ++j)
        ow[j] = (unsigned int)f32_to_bf16(acc[2*j] * inv)
              | ((unsigned int)f32_to_bf16(acc[2*j+1] * inv) << 16);
    *(uint4*)(agg16 + (size_t)node * HID + l16 * 8) = o;
}

// ---------------------------------------------------------------------------
// Residual MLP via bf16 MFMA, LDS-staged weights, 128 rows/block.
// Residual v is read from the interleaved qv buffer (offset 128, stride 256).
// ---------------------------------------------------------------------------
__global__ __launch_bounds__(256) void mlp_mfma_kernel(
    const ushort* __restrict__ agg16, const ushort* __restrict__ qv16,
    const ushort* __restrict__ W1_16, const float* __restrict__ b1,
    const ushort* __restrict__ W2_16, const float* __restrict__ b2,
    float* __restrict__ out)
{
    __shared__ ushort wlds[16384];    // 32 KB: W1, then W2
    __shared__ ushort h1s[16384];     // 32 KB: 8 tiles x 2048 ushorts (frag order)
    const int tid  = threadIdx.x;
    const int wave = tid >> 6;
    const int lane = tid & 63;
    const int row0 = blockIdx.x * 128 + wave * 32;
    const int lrow = lane & 15;
    const int lk   = (lane >> 4) * 8;
    const int crow = (lane >> 4) * 4;

    // phase 0: load agg A-fragments (2 tiles x 4 ks)
    short8 afrag[2][4];
    bool tvalid[2];
    #pragma unroll
    for (int r = 0; r < 2; ++r) {
        int rr = row0 + r * 16;
        tvalid[r] = (rr < N_NODES);
        const ushort* arow = agg16 + (size_t)((tvalid[r] ? rr : 0) + lrow) * HID + lk;
        #pragma unroll
        for (int ks = 0; ks < 4; ++ks)
            afrag[r][ks] = *(const short8*)(arow + ks * 32);
    }

    stage_w_frag(W1_16, wlds, tid);
    __syncthreads();

    // phase 1: h1 = relu(agg @ W1.T + b1) -> h1s in A-fragment order
    {
        floatx4 acc[2][8];
        #pragma unroll
        for (int r = 0; r < 2; ++r)
            #pragma unroll
            for (int t = 0; t < 8; ++t) acc[r][t] = (floatx4)(0.f);
        #pragma unroll
        for (int ks = 0; ks < 4; ++ks) {
            short8 B[8];
            #pragma unroll
            for (int t = 0; t < 8; ++t)
                B[t] = *(const short8*)&wlds[(ks * 8 + t) * 512 + lane * 8];
            #pragma unroll
            for (int t = 0; t < 8; ++t) {
                acc[0][t] = __builtin_amdgcn_mfma_f32_16x16x32_bf16(B[t], afrag[0][ks], acc[0][t], 0, 0, 0);
                acc[1][t] = __builtin_amdgcn_mfma_f32_16x16x32_bf16(B[t], afrag[1][ks], acc[1][t], 0, 0, 0);
            }
        }
        #pragma unroll
        for (int r = 0; r < 2; ++r) {
            ushort* tile = &h1s[(wave * 2 + r) * 2048];
            #pragma unroll
            for (int t = 0; t < 8; ++t) {
                float4 bias = *(const float4*)(b1 + t * 16 + crow);
                ushort4 o;
                o.x = f32_to_bf16(fmaxf(acc[r][t][0] + bias.x, 0.f));
                o.y = f32_to_bf16(fmaxf(acc[r][t][1] + bias.y, 0.f));
                o.z = f32_to_bf16(fmaxf(acc[r][t][2] + bias.z, 0.f));
                o.w = f32_to_bf16(fmaxf(acc[r][t][3] + bias.w, 0.f));
                int ks   = t >> 1;
                int quad = (t & 1) * 2 + (crow >> 3);
                int j0   = crow & 4;
                *(ushort4*)(tile + (ks * 64 + quad * 16 + lrow) * 8 + j0) = o;
            }
        }
    }
    __syncthreads();                    // h1 written, wlds reads done
    stage_w_frag(W2_16, wlds, tid);     // overwrite with W2
    __syncthreads();

    // phase 2: h2 = relu(h1 @ W2.T + b2); out = v + h2
    {
        short8 hfrag[2][4];
        #pragma unroll
        for (int r = 0; r < 2; ++r) {
            const ushort* tile = &h1s[(wave * 2 + r) * 2048];
            #pragma unroll
            for (int ks = 0; ks < 4; ++ks)
                hfrag[r][ks] = *(const short8*)(tile + (ks * 64 + lane) * 8);
        }
        floatx4 acc[2][8];
        #pragma unroll
        for (int r = 0; r < 2; ++r)
            #pragma unroll
            for (int t = 0; t < 8; ++t) acc[r][t] = (floatx4)(0.f);
        #pragma unroll
        for (int ks = 0; ks < 4; ++ks) {
            short8 B[8];
            #pragma unroll
            for (int t = 0; t < 8; ++t)
                B[t] = *(const short8*)&wlds[(ks * 8 + t) * 512 + lane * 8];
            #pragma unroll
            for (int t = 0; t < 8; ++t) {
                acc[0][t] = __builtin_amdgcn_mfma_f32_16x16x32_bf16(B[t], hfrag[0][ks], acc[0][t], 0, 0, 0);
                acc[1][t] = __builtin_amdgcn_mfma_f32_16x16x32_bf16(B[t], hfrag[1][ks], acc[1][t], 0, 0, 0);
            }
        }
        #pragma unroll
        for (int r = 0; r < 2; ++r) {
            if (tvalid[r]) {
                const size_t nrow = (size_t)(row0 + r * 16 + lrow);
                const ushort* vrow = qv16 + nrow * 256 + 128;
                float* orow = out + nrow * HID;
                #pragma unroll
                for (int t = 0; t < 8; ++t) {
                    float4 bias = *(const float4*)(b2 + t * 16 + crow);
                    ushort4 vv = *(const ushort4*)(vrow + t * 16 + crow);
                    float4 o;
                    o.x = bf16_bits_to_f32(vv.x) + fmaxf(acc[r][t][0] + bias.x, 0.f);
                    o.y = bf16_bits_to_f32(vv.y) + fmaxf(acc[r][t][1] + bias.y, 0.f);
                    o.z = bf16_bits_to_f32(vv.z) + fmaxf(acc[r][t][2] + bias.z, 0.f);
                    o.w = bf16_bits_to_f32(vv.w) + fmaxf(acc[r][t][3] + bias.w, 0.f);
                    *(float4*)(orow + t * 16 + crow) = o;
                }
            }
        }
    }
}

extern "C" void kernel_launch(void* const* d_in, const int* in_sizes, int n_in,
                              void* d_out, int out_size, void* d_ws, size_t ws_size,
                              hipStream_t stream) {
    const float* feats  = (const float*)d_in[0];
    const int*   idx_kj = (const int*)d_in[1];
    const int*   idx_ji = (const int*)d_in[2];
    const float* Wv     = (const float*)d_in[3];
    const float* Wq     = (const float*)d_in[4];
    const float* Wk     = (const float*)d_in[5];
    const float* W1     = (const float*)d_in[6];
    const float* b1     = (const float*)d_in[7];
    const float* W2     = (const float*)d_in[8];
    const float* b2     = (const float*)d_in[9];
    float* out = (float*)d_out;

    // workspace layout
    ushort* qv16    = (ushort*)d_ws;                        // [N][256]: q | v
    ushort* k16     = qv16    + (size_t)N_NODES * 256;      // [N][128]
    ushort* agg16   = k16     + (size_t)N_NODES * HID;      // [N][128]
    ushort* Wq16    = agg16   + (size_t)N_NODES * HID;
    ushort* Wk16    = Wq16 + HID * HID;
    ushort* Wv16    = Wk16 + HID * HID;
    ushort* W116    = Wv16 + HID * HID;
    ushort* W216    = W116 + HID * HID;
    int* count      = (int*)(W216 + HID * HID);
    int* offsets    = count + N_NODES;
    int* cursor     = offsets + N_NODES;
    int* blocksum   = cursor + N_NODES;
    int* edge_kj    = blocksum + ((SCAN_NB + 3) & ~3);

    hipMemsetAsync(count, 0, N_NODES * sizeof(int), stream);

    cvt_w_kernel<<<(5 * HID * HID + 255) / 256, 256, 0, stream>>>(
        Wq, Wk, Wv, W1, W2, Wq16, Wk16, Wv16, W116, W216);

    qkv_mfma_kernel<<<(N_NODES + 127) / 128, 256, 0, stream>>>(
        feats, Wq16, Wk16, Wv16, qv16, k16);

    hist_kernel<<<(M_EDGES + 255) / 256, 256, 0, stream>>>(idx_ji, count);
    scan_blocksum_kernel<<<SCAN_NB, 256, 0, stream>>>(count, blocksum);
    scan_top_kernel<<<1, 128, 0, stream>>>(blocksum);
    scan_write_kernel<<<SCAN_NB, 256, 0, stream>>>(count, blocksum, offsets, cursor);
    fill_kernel<<<(M_EDGES + 255) / 256, 256, 0, stream>>>(idx_ji, idx_kj, cursor, edge_kj);

    aggregate_kernel<<<((size_t)N_NODES * 16 + 255) / 256, 256, 0, stream>>>(
        edge_kj, offsets, count, qv16, k16, agg16);

    mlp_mfma_kernel<<<(N_NODES + 127) / 128, 256, 0, stream>>>(
        agg16, qv16, W116, b1, W216, b2, out);
}